// Round 5
// baseline (10039.967 us; speedup 1.0000x reference)
//
#include <hip/hip_runtime.h>
#include <cmath>

// float offsets in ws
#define WS_AK 0
#define WS_AV 300
#define WS_U  600   // ushort region starts here

// ushort offsets relative to uw = (ushort*)(ws + WS_U)
#define UW_DKT 0        // DkT B-frags [4kt][64ng][64][8]  (k=chan128, n=key1024)
#define UW_DVT 131072   // DvT B-frags [32kv][7nt][64][8]  (k=key1024, n=chan112; col100=1)
#define UW_AKT 245760   // AkT B-frags [4kt][64][8]        (k=chan128, n=16: 3 real)
#define UW_QW  247808   // q_w frags  kt4 x nt7
#define UW_OW  262144   // o_w frags  kt4 x nt7
#define UW_W1  276480   // + d*51200  kt4 x nt25
#define UW_W2  378880   // + d*50176  kt14 x nt7
#define UW_AIW 479232   // + (d*3+wsel)*16384  kt4 x nt8 (head-padded)
#define UW_AOW 577536   // + d*14336  kt4 x nt7 (head-padded k'=h*32+dh)
#define UW_WCNT 358400  // elements written by pre_wfrag (from UW_QW)

typedef __attribute__((ext_vector_type(8))) short short8;
typedef __attribute__((ext_vector_type(4))) float f32x4;

#define MFMA(a, b, c) __builtin_amdgcn_mfma_f32_16x16x32_bf16((a), (b), (c), 0, 0, 0)

static __device__ __forceinline__ unsigned short f2bf(float f) {
  unsigned int u = __float_as_uint(f);
  u += 0x7FFF + ((u >> 16) & 1);   // RNE
  return (unsigned short)(u >> 16);
}
static __device__ __forceinline__ f32x4 zero4() { return (f32x4){0.f, 0.f, 0.f, 0.f}; }

// ---------------------------------------------------------------------------
__global__ void pre_amat_kernel(const float* __restrict__ proj_w,
                                const float* __restrict__ k_w,
                                const float* __restrict__ v_w,
                                float* __restrict__ ws) {
  int idx = blockIdx.x * blockDim.x + threadIdx.x;
  if (idx >= 600) return;
  int sel = idx / 300;
  int rem = idx % 300;
  int c = rem / 100, m = rem % 100;
  const float* w = sel ? v_w : k_w;
  float acc = 0.f;
  for (int n = 0; n < 100; ++n) acc += proj_w[n * 131 + c] * w[m * 100 + n];
  ws[(sel ? WS_AV : WS_AK) + c * 100 + m] = acc;
}

// AkT frags: B[k][n] = Ak[n][k] (n<3), bf16
__global__ void pre_akt_kernel(const float* __restrict__ ws,
                               unsigned short* __restrict__ uw) {
  int idx = blockIdx.x * blockDim.x + threadIdx.x;
  if (idx >= 2048) return;
  int kt = idx >> 9, lane = (idx >> 3) & 63, j = idx & 7;
  int k = kt * 32 + (lane >> 4) * 8 + j;
  int n = lane & 15;
  float val = (k < 100 && n < 3) ? ws[WS_AK + n * 100 + k] : 0.f;
  uw[UW_AKT + idx] = f2bf(val);
}

// Zero/one pads: DkT k=100..127 -> 0 ; DvT n=100..111 -> (n==100 ? 1 : 0)
__global__ void pre_fill_kernel(unsigned short* __restrict__ uw) {
  int idx = blockIdx.x * blockDim.x + threadIdx.x;
  if (idx >= 40960) return;
  if (idx < 28672) {
    int m = 100 + idx % 28, p = idx / 28;
    int kt = m >> 5, ng = p >> 4;
    int lane = (((m & 31) >> 3) << 4) + (p & 15);
    uw[UW_DKT + ((kt * 64 + ng) * 64 + lane) * 8 + (m & 7)] = 0;
  } else {
    int r = idx - 28672;
    int m = 100 + r % 12, p = r / 12;
    int kv = p >> 5, nt = m >> 4;
    int lane = (((p & 31) >> 3) << 4) + (m & 15);
    uw[UW_DVT + ((kv * 7 + nt) * 64 + lane) * 8 + (p & 7)] =
        (m == 100) ? (unsigned short)0x3F80 : (unsigned short)0;
  }
}

// ---------------------------------------------------------------------------
// Dk/Dv (batch-independent K/V parts) straight into B-frag layouts (bf16)
// ---------------------------------------------------------------------------
__global__ void pre_dmat_kernel(const float* __restrict__ fm,
                                const float* __restrict__ proj_w,
                                const float* __restrict__ proj_b,
                                const float* __restrict__ k_w,
                                const float* __restrict__ k_b,
                                const float* __restrict__ v_w,
                                const float* __restrict__ v_b,
                                unsigned short* __restrict__ uw) {
  __shared__ float pos[8][128];
  __shared__ float tc[8][100];
  int p0 = blockIdx.x * 8;
  int tid = threadIdx.x;
  for (int idx = tid; idx < 1024; idx += 256) {
    int pl = idx >> 7, f = idx & 127;
    int p = p0 + pl;
    float cx = (float)(p & 31) * (1.f / 31.f);
    float cy = (float)(p >> 5) * (1.f / 31.f);
    int fi = f & 63;
    float pr = cx * fm[fi] + cy * fm[64 + fi];
    float ang = 6.2831853071795864769f * pr;
    pos[pl][f] = (f < 64) ? cosf(ang) : sinf(ang);
  }
  __syncthreads();
  for (int idx = tid; idx < 800; idx += 256) {
    int pl = idx / 100, n = idx % 100;
    float acc = proj_b[n];
    const float* pw = proj_w + n * 131 + 3;
    for (int f = 0; f < 128; ++f) acc += pos[pl][f] * pw[f];
    tc[pl][n] = acc;
  }
  __syncthreads();
  for (int idx = tid; idx < 1600; idx += 256) {
    int sel = idx / 800;
    int rem = idx % 800;
    int pl = rem / 100, m = rem % 100;
    int p = p0 + pl;
    const float* w = sel ? v_w : k_w;
    float acc = sel ? v_b[m] : k_b[m];
    for (int n = 0; n < 100; ++n) acc += tc[pl][n] * w[m * 100 + n];
    if (sel) {   // DvT: k=key p, n=chan m
      int kv = p >> 5, nt = m >> 4;
      int lane = (((p & 31) >> 3) << 4) + (m & 15);
      uw[UW_DVT + ((kv * 7 + nt) * 64 + lane) * 8 + (p & 7)] = f2bf(acc);
    } else {     // DkT: k=chan m, n=key p
      int kt = m >> 5, ng = p >> 4;
      int lane = (((m & 31) >> 3) << 4) + (p & 15);
      uw[UW_DKT + ((kt * 64 + ng) * 64 + lane) * 8 + (m & 7)] = f2bf(acc);
    }
  }
}

// ---------------------------------------------------------------------------
__global__ void pre_wfrag_kernel(const float* __restrict__ q_w,
                                 const float* __restrict__ o_w,
                                 const float* __restrict__ mlp_w1,
                                 const float* __restrict__ mlp_w2,
                                 const float* __restrict__ attn_in_w,
                                 const float* __restrict__ attn_out_w,
                                 unsigned short* __restrict__ uw) {
  int idx = blockIdx.x * 256 + threadIdx.x;
  if (idx >= UW_WCNT) return;
  float val = 0.f;
  if (idx < 14336) {
    int rem = idx;
    int kt = rem / 3584; rem %= 3584;
    int nt = rem / 512;  rem %= 512;
    int lane = rem >> 3, j = rem & 7;
    int k = kt * 32 + (lane >> 4) * 8 + j;
    int n = nt * 16 + (lane & 15);
    if (k < 100 && n < 100) val = q_w[n * 100 + k];
  } else if (idx < 28672) {
    int rem = idx - 14336;
    int kt = rem / 3584; rem %= 3584;
    int nt = rem / 512;  rem %= 512;
    int lane = rem >> 3, j = rem & 7;
    int k = kt * 32 + (lane >> 4) * 8 + j;
    int n = nt * 16 + (lane & 15);
    if (k < 100 && n < 100) val = o_w[n * 100 + k];
  } else if (idx < 131072) {
    int off = idx - 28672;
    int dd = off / 51200;
    int rem = off % 51200;
    int kt = rem / 12800; rem %= 12800;
    int nt = rem / 512;   rem %= 512;
    int lane = rem >> 3, j = rem & 7;
    int k = kt * 32 + (lane >> 4) * 8 + j;
    int n = nt * 16 + (lane & 15);
    if (k < 100) val = mlp_w1[dd * 40000 + n * 100 + k];
  } else if (idx < 231424) {
    int off = idx - 131072;
    int dd = off / 50176;
    int rem = off % 50176;
    int kt = rem / 3584; rem %= 3584;
    int nt = rem / 512;  rem %= 512;
    int lane = rem >> 3, j = rem & 7;
    int k = kt * 32 + (lane >> 4) * 8 + j;
    int n = nt * 16 + (lane & 15);
    if (k < 400 && n < 100) val = mlp_w2[dd * 40000 + n * 400 + k];
  } else if (idx < 329728) {
    int off = idx - 231424;
    int dw = off / 16384;
    int rem = off % 16384;
    int dd = dw / 3, wsel = dw % 3;
    int kt = rem / 4096; rem %= 4096;
    int nt = rem / 512;  rem %= 512;
    int lane = rem >> 3, j = rem & 7;
    int k = kt * 32 + (lane >> 4) * 8 + j;
    int np = nt * 16 + (lane & 15);
    int hh = np >> 5, dh = np & 31;
    if (k < 100 && dh < 25)
      val = attn_in_w[dd * 30000 + (wsel * 100 + hh * 25 + dh) * 100 + k];
  } else {
    int off = idx - 329728;
    int dd = off / 14336;
    int rem = off % 14336;
    int kt = rem / 3584; rem %= 3584;
    int nt = rem / 512;  rem %= 512;
    int lane = rem >> 3, j = rem & 7;
    int kp = kt * 32 + (lane >> 4) * 8 + j;
    int hh = kp >> 5, dh = kp & 31;
    int n = nt * 16 + (lane & 15);
    if (dh < 25 && n < 100)
      val = attn_out_w[dd * 10000 + n * 100 + hh * 25 + dh];
  }
  uw[UW_QW + idx] = f2bf(val);
}

// ---------------------------------------------------------------------------
// Main kernel: 1 block/batch, 512 threads (8 waves), 2 blocks/CU.
// Residual lat in MFMA C-layout f32 regs latC[mt2][nt][rg].
// Cross-attn: S = q.DkT (global frags) + rank-3 x-correction (VALU);
//             O = P.DvT (global frags) + pxa.Av fixup. Tile loop: 0 barriers.
// ---------------------------------------------------------------------------
__launch_bounds__(512, 4)
__global__ void perceiver_kernel(
    const float* __restrict__ x,
    const float* __restrict__ latents,
    const float* __restrict__ latent_pos,
    const float* __restrict__ q_b, const float* __restrict__ o_b,
    const float* __restrict__ ln1_g, const float* __restrict__ ln1_b,
    const float* __restrict__ attn_in_b, const float* __restrict__ attn_out_b,
    const float* __restrict__ ln2_g, const float* __restrict__ ln2_b,
    const float* __restrict__ mlp_b1, const float* __restrict__ mlp_b2,
    const float* __restrict__ ws,
    float* __restrict__ out) {
  __shared__ __align__(16) float s_pool[19908];
  float* s_sm = s_pool;                        // 2500 floats
  float* Rf   = s_pool + 2500;                 // 17408 floats = 34816 ushorts
  unsigned short* R   = (unsigned short*)Rf;
  unsigned short* s_M = R;                     // [256][132] bf16 staging
  // MHA aliases
  unsigned short* sQh   = R;                   // [256][36]
  unsigned short* kfrag = R + 9216;            // 8192
  unsigned short* vfrag = R + 17408;           // 8192
  unsigned short* sPm   = R + 25600;           // [256][36]

  const int tid  = threadIdx.x;
  const int b    = blockIdx.x;
  const int lane = tid & 63;
  const int wv   = tid >> 6;
  const int li   = lane & 15;
  const int lg   = lane >> 4;
  const unsigned short* uw = (const unsigned short*)(ws + WS_U);
  unsigned short* sPw = R + wv * 4224;         // per-wave P scratch [32][76] in own slice

  // ---- stage hot constants ----
  for (int i = tid; i < 200; i += 512) {
    s_sm[i] = ln1_g[i]; s_sm[200 + i] = ln1_b[i];
    s_sm[400 + i] = ln2_g[i]; s_sm[600 + i] = ln2_b[i];
  }
  for (int i = tid; i < 600; i += 512) s_sm[800 + i] = attn_in_b[i];
  for (int i = tid; i < 800; i += 512) s_sm[1400 + i] = mlp_b1[i];
  for (int i = tid; i < 300; i += 512) s_sm[2200 + i] = ws[WS_AV + i];
  __syncthreads();

  // ---- residual in C-layout regs ----
  f32x4 latC[2][7];
  #pragma unroll
  for (int mt2 = 0; mt2 < 2; ++mt2)
    #pragma unroll
    for (int nt = 0; nt < 7; ++nt) {
      const int col = nt * 16 + li;
      #pragma unroll
      for (int rg = 0; rg < 4; ++rg) {
        const int row = (2 * wv + mt2) * 16 + lg * 4 + rg;
        latC[mt2][nt][rg] = (col < 100)
            ? latents[row * 100 + col] + latent_pos[row * 100 + col] : 0.f;
      }
    }

  const float* xb = x + (long)b * 3072;

  // LN helper: latC -> s_M (bf16, zero-padded cols 100..127)
  auto ln_stage = [&](const float* gg, const float* bb) {
    #pragma unroll
    for (int mt2 = 0; mt2 < 2; ++mt2)
      #pragma unroll
      for (int rg = 0; rg < 4; ++rg) {
        float s = 0.f, sq = 0.f;
        #pragma unroll
        for (int nt = 0; nt < 7; ++nt) {
          const int col = nt * 16 + li;
          if (col < 100) { const float v = latC[mt2][nt][rg]; s += v; sq += v * v; }
        }
        s += __shfl_xor(s, 1); sq += __shfl_xor(sq, 1);
        s += __shfl_xor(s, 2); sq += __shfl_xor(sq, 2);
        s += __shfl_xor(s, 4); sq += __shfl_xor(sq, 4);
        s += __shfl_xor(s, 8); sq += __shfl_xor(sq, 8);
        const float mu = s * 0.01f;
        const float rs = rsqrtf(sq * 0.01f - mu * mu + 1e-5f);
        const int row = (2 * wv + mt2) * 16 + lg * 4 + rg;
        #pragma unroll
        for (int nt = 0; nt < 7; ++nt) {
          const int col = nt * 16 + li;
          s_M[row * 132 + col] = (col < 100)
              ? f2bf((latC[mt2][nt][rg] - mu) * rs * gg[col] + bb[col]) : 0;
        }
        s_M[row * 132 + 112 + li] = 0;
      }
  };

  for (int it = 0; it < 8; ++it) {
    //=================== cross attention (barrier-free) ===================
    // stage lat -> s_M (own rows)
    #pragma unroll
    for (int mt2 = 0; mt2 < 2; ++mt2)
      #pragma unroll
      for (int rg = 0; rg < 4; ++rg) {
        const int row = (2 * wv + mt2) * 16 + lg * 4 + rg;
        #pragma unroll
        for (int nt = 0; nt < 7; ++nt) {
          const int col = nt * 16 + li;
          s_M[row * 132 + col] = (col < 100) ? f2bf(latC[mt2][nt][rg]) : 0;
        }
        s_M[row * 132 + 112 + li] = 0;
      }

    // q-proj: q_s = (lat @ q_w^T + q_b) * 0.1 -> s_M (own rows)
    {
      short8 aq[2][4];
      #pragma unroll
      for (int mt2 = 0; mt2 < 2; ++mt2)
        #pragma unroll
        for (int kt = 0; kt < 4; ++kt)
          aq[mt2][kt] = *(const short8*)(s_M + ((2 * wv + mt2) * 16 + li) * 132 + kt * 32 + lg * 8);
      #pragma unroll
      for (int nt = 0; nt < 7; ++nt) {
        f32x4 a0 = zero4(), a1 = zero4();
        #pragma unroll
        for (int kt = 0; kt < 4; ++kt) {
          short8 bw = *(const short8*)(uw + UW_QW + ((kt * 7 + nt) * 64 + lane) * 8);
          a0 = MFMA(aq[0][kt], bw, a0);
          a1 = MFMA(aq[1][kt], bw, a1);
        }
        const int col = nt * 16 + li;
        const float qb = (col < 100) ? q_b[col] : 0.f;
        #pragma unroll
        for (int rg = 0; rg < 4; ++rg) {
          const int r0 = (2 * wv) * 16 + lg * 4 + rg;
          const int r1 = (2 * wv + 1) * 16 + lg * 4 + rg;
          s_M[r0 * 132 + col] = (col < 100) ? f2bf((a0[rg] + qb) * 0.1f) : 0;
          s_M[r1 * 132 + col] = (col < 100) ? f2bf((a1[rg] + qb) * 0.1f) : 0;
        }
      }
    }

    // q A-frags (registers; s_M slice becomes dead -> reused as sPw)
    short8 aq2[2][4];
    #pragma unroll
    for (int mt2 = 0; mt2 < 2; ++mt2)
      #pragma unroll
      for (int kt = 0; kt < 4; ++kt)
        aq2[mt2][kt] = *(const short8*)(s_M + ((2 * wv + mt2) * 16 + li) * 132 + kt * 32 + lg * 8);

    // qa = q_s . Ak^T  (C-layout, cols 0..2 valid in lanes li<3)
    f32x4 qa0v = zero4(), qa1v = zero4();
    #pragma unroll
    for (int kt = 0; kt < 4; ++kt) {
      short8 bw = *(const short8*)(uw + UW_AKT + (kt * 64 + lane) * 8);
      qa0v = MFMA(aq2[0][kt], bw, qa0v);
      qa1v = MFMA(aq2[1][kt], bw, qa1v);
    }

    // O = exp(S) @ [Dv|1]  + rank-3 corrections
    f32x4 O[2][7];
    #pragma unroll
    for (int a0 = 0; a0 < 2; ++a0)
      #pragma unroll
      for (int a1 = 0; a1 < 7; ++a1) O[a0][a1] = zero4();
    float pxa[2][4][3];
    #pragma unroll
    for (int a0 = 0; a0 < 2; ++a0)
      #pragma unroll
      for (int a1 = 0; a1 < 4; ++a1)
        #pragma unroll
        for (int a2 = 0; a2 < 3; ++a2) pxa[a0][a1][a2] = 0.f;

    for (int t0 = 0; t0 < 1024; t0 += 64) {
      // broadcast qa for own rows (transient)
      float qa3[2][4][3];
      #pragma unroll
      for (int rg = 0; rg < 4; ++rg)
        #pragma unroll
        for (int ch = 0; ch < 3; ++ch) {
          qa3[0][rg][ch] = __shfl(qa0v[rg], (lane & 48) + ch);
          qa3[1][rg][ch] = __shfl(qa1v[rg], (lane & 48) + ch);
        }
      // S + exp + pxa + P-stage per ntk
      #pragma unroll
      for (int ntk = 0; ntk < 4; ++ntk) {
        f32x4 s0 = zero4(), s1 = zero4();
        #pragma unroll
        for (int kt = 0; kt < 4; ++kt) {
          short8 bk = *(const short8*)(uw + UW_DKT + ((kt * 64 + (t0 >> 4) + ntk) * 64 + lane) * 8);
          s0 = MFMA(aq2[0][kt], bk, s0);
          s1 = MFMA(aq2[1][kt], bk, s1);
        }
        const int p = t0 + ntk * 16 + li;
        const float xr = xb[p], xg = xb[1024 + p], xv = xb[2048 + p];
        #pragma unroll
        for (int rg = 0; rg < 4; ++rg) {
          float sv0 = s0[rg] + qa3[0][rg][0] * xr + qa3[0][rg][1] * xg + qa3[0][rg][2] * xv;
          float sv1 = s1[rg] + qa3[1][rg][0] * xr + qa3[1][rg][1] * xg + qa3[1][rg][2] * xv;
          float pe0 = __expf(sv0);
          float pe1 = __expf(sv1);
          pxa[0][rg][0] += pe0 * xr; pxa[0][rg][1] += pe0 * xg; pxa[0][rg][2] += pe0 * xv;
          pxa[1][rg][0] += pe1 * xr; pxa[1][rg][1] += pe1 * xg; pxa[1][rg][2] += pe1 * xv;
          sPw[(lg * 4 + rg) * 76 + ntk * 16 + li]        = f2bf(pe0);
          sPw[(16 + lg * 4 + rg) * 76 + ntk * 16 + li]   = f2bf(pe1);
        }
      }
      // PV vs global DvT frags
      short8 ap00 = *(const short8*)(sPw + li * 76 + lg * 8);
      short8 ap01 = *(const short8*)(sPw + li * 76 + 32 + lg * 8);
      short8 ap10 = *(const short8*)(sPw + (16 + li) * 76 + lg * 8);
      short8 ap11 = *(const short8*)(sPw + (16 + li) * 76 + 32 + lg * 8);
      const int kv = t0 >> 5;
      #pragma unroll
      for (int nt = 0; nt < 7; ++nt) {
        short8 bv0 = *(const short8*)(uw + UW_DVT + ((kv * 7 + nt) * 64 + lane) * 8);
        short8 bv1 = *(const short8*)(uw + UW_DVT + (((kv + 1) * 7 + nt) * 64 + lane) * 8);
        O[0][nt] = MFMA(ap00, bv0, O[0][nt]);
        O[0][nt] = MFMA(ap01, bv1, O[0][nt]);
        O[1][nt] = MFMA(ap10, bv0, O[1][nt]);
        O[1][nt] = MFMA(ap11, bv1, O[1][nt]);
      }
    }

    // reduce pxa over the 16-lane key groups
    #pragma unroll
    for (int mt2 = 0; mt2 < 2; ++mt2)
      #pragma unroll
      for (int rg = 0; rg < 4; ++rg)
        #pragma unroll
        for (int ch = 0; ch < 3; ++ch) {
          float v = pxa[mt2][rg][ch];
          v += __shfl_xor(v, 1);
          v += __shfl_xor(v, 2);
          v += __shfl_xor(v, 4);
          v += __shfl_xor(v, 8);
          pxa[mt2][rg][ch] = v;
        }
    // O += pxa . Av  (cols < 100; col 100 (=l) untouched since Av has no col-100 term)
    #pragma unroll
    for (int mt2 = 0; mt2 < 2; ++mt2)
      #pragma unroll
      for (int nt = 0; nt < 7; ++nt) {
        const int col = nt * 16 + li;
        if (col < 100) {
          const float av0 = s_sm[2200 + col], av1 = s_sm[2300 + col], av2 = s_sm[2400 + col];
          #pragma unroll
          for (int rg = 0; rg < 4; ++rg)
            O[mt2][nt][rg] += pxa[mt2][rg][0] * av0 + pxa[mt2][rg][1] * av1 + pxa[mt2][rg][2] * av2;
        }
      }

    // normalize (l at col 100 -> nt=6, li==4), write o_in -> s_M (own rows)
    #pragma unroll
    for (int mt2 = 0; mt2 < 2; ++mt2)
      #pragma unroll
      for (int rg = 0; rg < 4; ++rg) {
        const float lv = __shfl(O[mt2][6][rg], (lane & 48) + 4);
        const float linv = 1.0f / lv;
        const int row = (2 * wv + mt2) * 16 + lg * 4 + rg;
        #pragma unroll
        for (int nt = 0; nt < 7; ++nt) {
          const int col = nt * 16 + li;
          s_M[row * 132 + col] = (col < 100) ? f2bf(O[mt2][nt][rg] * linv) : 0;
        }
        s_M[row * 132 + 112 + li] = 0;
      }

    // o-proj -> latC (replace)
    {
      short8 ao[2][4];
      #pragma unroll
      for (int mt2 = 0; mt2 < 2; ++mt2)
        #pragma unroll
        for (int kt = 0; kt < 4; ++kt)
          ao[mt2][kt] = *(const short8*)(s_M + ((2 * wv + mt2) * 16 + li) * 132 + kt * 32 + lg * 8);
      #pragma unroll
      for (int nt = 0; nt < 7; ++nt) {
        f32x4 a0 = zero4(), a1 = zero4();
        #pragma unroll
        for (int kt = 0; kt < 4; ++kt) {
          short8 bw = *(const short8*)(uw + UW_OW + ((kt * 7 + nt) * 64 + lane) * 8);
          a0 = MFMA(ao[0][kt], bw, a0);
          a1 = MFMA(ao[1][kt], bw, a1);
        }
        const int col = nt * 16 + li;
        const float ob = (col < 100) ? o_b[col] : 0.f;
        #pragma unroll
        for (int rg = 0; rg < 4; ++rg) {
          latC[0][nt][rg] = (col < 100) ? a0[rg] + ob : 0.f;
          latC[1][nt][rg] = (col < 100) ? a1[rg] + ob : 0.f;
        }
      }
    }

    //=================== latent transformer ===================
    for (int d = 0; d < 2; ++d) {
      // ---- LN1 -> s_M (own rows)
      ln_stage(&s_sm[d * 100], &s_sm[200 + d * 100]);
      short8 ah[2][4];
      #pragma unroll
      for (int mt2 = 0; mt2 < 2; ++mt2)
        #pragma unroll
        for (int kt = 0; kt < 4; ++kt)
          ah[mt2][kt] = *(const short8*)(s_M + ((2 * wv + mt2) * 16 + li) * 132 + kt * 32 + lg * 8);

      // co init = lat + attn_out_b
      f32x4 co[2][7];
      #pragma unroll
      for (int nt = 0; nt < 7; ++nt) {
        const int col = nt * 16 + li;
        const float ob = (col < 100) ? attn_out_b[d * 100 + col] : 0.f;
        #pragma unroll
        for (int rg = 0; rg < 4; ++rg) {
          co[0][nt][rg] = (col < 100) ? latC[0][nt][rg] + ob : 0.f;
          co[1][nt][rg] = (col < 100) ? latC[1][nt][rg] + ob : 0.f;
        }
      }

      for (int h = 0; h < 4; ++h) {
        __syncthreads();   // prior reads of R complete before scratch writes
        #pragma unroll
        for (int ntd = 0; ntd < 2; ++ntd) {
          f32x4 cq0 = zero4(), cq1 = zero4(), ck0 = zero4(), ck1 = zero4(),
                cv0 = zero4(), cv1 = zero4();
          #pragma unroll
          for (int kt = 0; kt < 4; ++kt) {
            const int bidx = ((kt * 8 + h * 2 + ntd) * 64 + lane) * 8;
            short8 bq  = *(const short8*)(uw + UW_AIW + (d * 3 + 0) * 16384 + bidx);
            short8 bkk = *(const short8*)(uw + UW_AIW + (d * 3 + 1) * 16384 + bidx);
            short8 bvv = *(const short8*)(uw + UW_AIW + (d * 3 + 2) * 16384 + bidx);
            cq0 = MFMA(ah[0][kt], bq,  cq0); cq1 = MFMA(ah[1][kt], bq,  cq1);
            ck0 = MFMA(ah[0][kt], bkk, ck0); ck1 = MFMA(ah[1][kt], bkk, ck1);
            cv0 = MFMA(ah[0][kt], bvv, cv0); cv1 = MFMA(ah[1][kt], bvv, cv1);
          }
          const int dh = ntd * 16 + li;
          const bool ok = dh < 25;
          const float qb2 = ok ? s_sm[800 + d * 300 +       h * 25 + dh] : 0.f;
          const float kb2 = ok ? s_sm[800 + d * 300 + 100 + h * 25 + dh] : 0.f;
          const float vb2 = ok ? s_sm[800 + d * 300 + 200 + h * 25 + dh] : 0.f;
          #pragma unroll
          for (int mt2 = 0; mt2 < 2; ++mt2)
            #pragma unroll
            for (int rg = 0; rg < 4; ++rg) {
              const int rr = lg * 4 + rg;
              const int row = (2 * wv + mt2) * 16 + rr;
              const float q = mt2 ? cq1[rg] : cq0[rg];
              const float k = mt2 ? ck1[rg] : ck0[rg];
              const float v = mt2 ? cv1[rg] : cv0[rg];
              sQh[row * 36 + dh] = ok ? f2bf((q + qb2) * 0.2f) : 0;
              kfrag[((2 * wv + mt2) * 64 + (dh >> 3) * 16 + rr) * 8 + (dh & 7)] =
                  ok ? f2bf(k + kb2) : 0;
              vfrag[((wv * 2 + ntd) * 64 + (mt2 * 2 + (rr >> 3)) * 16 + li) * 8 + (rr & 7)] =
                  ok ? f2bf(v + vb2) : (unsigned short)((dh == 25) ? 0x3F80 : 0);
            }
        }
        __syncthreads();   // kfrag/vfrag visible

        short8 aqh0 = *(const short8*)(sQh + ((2 * wv + 0) * 16 + li) * 36 + lg * 8);
        short8 aqh1 = *(const short8*)(sQh + ((2 * wv + 1) * 16 + li) * 36 + lg * 8);
        f32x4 Oh00 = zero4(), Oh01 = zero4(), Oh10 = zero4(), Oh11 = zero4();
        for (int t = 0; t < 8; ++t) {
          short8 bk0 = *(const short8*)(kfrag + ((t * 2 + 0) * 64 + lane) * 8);
          short8 bk1 = *(const short8*)(kfrag + ((t * 2 + 1) * 64 + lane) * 8);
          f32x4 s00 = MFMA(aqh0, bk0, zero4());
          f32x4 s01 = MFMA(aqh0, bk1, zero4());
          f32x4 s10 = MFMA(aqh1, bk0, zero4());
          f32x4 s11 = MFMA(aqh1, bk1, zero4());
          #pragma unroll
          for (int rg = 0; rg < 4; ++rg) {
            const int r0 = (2 * wv) * 16 + lg * 4 + rg;
            const int r1 = (2 * wv + 1) * 16 + lg * 4 + rg;
            sPm[r0 * 36 + li]      = f2bf(__expf(s00[rg]));
            sPm[r0 * 36 + 16 + li] = f2bf(__expf(s01[rg]));
            sPm[r1 * 36 + li]      = f2bf(__expf(s10[rg]));
            sPm[r1 * 36 + 16 + li] = f2bf(__expf(s11[rg]));
          }
          short8 ap0 = *(const short8*)(sPm + ((2 * wv + 0) * 16 + li) * 36 + lg * 8);
          short8 ap1 = *(const short8*)(sPm + ((2 * wv + 1) * 16 + li) * 36 + lg * 8);
          short8 bv0 = *(const short8*)(vfrag + ((t * 2 + 0) * 64 + lane) * 8);
          short8 bv1 = *(const short8*)(vfrag + ((t * 2 + 1) * 64 + lane) * 8);
          Oh00 = MFMA(ap0, bv0, Oh00); Oh01 = MFMA(ap0, bv1, Oh01);
          Oh10 = MFMA(ap1, bv0, Oh10); Oh11 = MFMA(ap1, bv1, Oh11);
        }
        #pragma unroll
        for (int mt2 = 0; mt2 < 2; ++mt2)
          #pragma unroll
          for (int rg = 0; rg < 4; ++rg) {
            const f32x4& o0 = mt2 ? Oh10 : Oh00;
            const f32x4& o1 = mt2 ? Oh11 : Oh01;
            const float lv = __shfl(o1[rg], (lane & 48) + 9);
            const float linv = 1.0f / lv;
            const int row = (2 * wv + mt2) * 16 + lg * 4 + rg;
            sPm[row * 36 + li]      = (li < 25)      ? f2bf(o0[rg] * linv) : 0;
            sPm[row * 36 + 16 + li] = (16 + li < 25) ? f2bf(o1[rg] * linv) : 0;
          }
        short8 ao0 = *(const short8*)(sPm + ((2 * wv + 0) * 16 + li) * 36 + lg * 8);
        short8 ao1 = *(const short8*)(sPm + ((2 * wv + 1) * 16 + li) * 36 + lg * 8);
        #pragma unroll
        for (int nt = 0; nt < 7; ++nt) {
          short8 bw = *(const short8*)(uw + UW_AOW + d * 14336 + ((h * 7 + nt) * 64 + lane) * 8);
          co[0][nt] = MFMA(ao0, bw, co[0][nt]);
          co[1][nt] = MFMA(ao1, bw, co[1][nt]);
        }
      }
      __syncthreads();   // all scratch reads done

      #pragma unroll
      for (int mt2 = 0; mt2 < 2; ++mt2)
        #pragma unroll
        for (int nt = 0; nt < 7; ++nt) latC[mt2][nt] = co[mt2][nt];

      // ---- LN2 -> s_M, MLP
      ln_stage(&s_sm[400 + d * 100], &s_sm[600 + d * 100]);
      short8 ahm[2][4];
      #pragma unroll
      for (int mt2 = 0; mt2 < 2; ++mt2)
        #pragma unroll
        for (int kt = 0; kt < 4; ++kt)
          ahm[mt2][kt] = *(const short8*)(s_M + ((2 * wv + mt2) * 16 + li) * 132 + kt * 32 + lg * 8);

      f32x4 c2[2][7];
      #pragma unroll
      for (int nt = 0; nt < 7; ++nt) {
        const int col = nt * 16 + li;
        const float b2 = (col < 100) ? mlp_b2[d * 100 + col] : 0.f;
        #pragma unroll
        for (int rg = 0; rg < 4; ++rg) {
          c2[0][nt][rg] = (col < 100) ? latC[0][nt][rg] + b2 : 0.f;
          c2[1][nt][rg] = (col < 100) ? latC[1][nt][rg] + b2 : 0.f;
        }
      }

      const int w1off = UW_W1 + d * 51200;
      const int w2off = UW_W2 + d * 50176;
      for (int chunk = 0; chunk < 3; ++chunk) {
        #pragma unroll
        for (int ntl = 0; ntl < 8; ++ntl) {
          f32x4 a0 = zero4(), a1 = zero4();
          #pragma unroll
          for (int kt = 0; kt < 4; ++kt) {
            short8 bw = *(const short8*)(uw + w1off + ((kt * 25 + (chunk * 8 + ntl)) * 64 + lane) * 8);
            a0 = MFMA(ahm[0][kt], bw, a0);
            a1 = MFMA(ahm[1][kt], bw, a1);
          }
          const int col = ntl * 16 + li;
          const float bias = s_sm[1400 + d * 400 + chunk * 128 + col];
          #pragma unroll
          for (int rg = 0; rg < 4; ++rg) {
            const int r0 = (2 * wv) * 16 + lg * 4 + rg;
            const int r1 = (2 * wv + 1) * 16 + lg * 4 + rg;
            float h0 = a0[rg] + bias, h1 = a1[rg] + bias;
            s_M[r0 * 132 + col] = f2bf(0.5f * h0 * (1.0f + erff(h0 * 0.70710678118654752f)));
            s_M[r1 * 132 + col] = f2bf(0.5f * h1 * (1.0f + erff(h1 * 0.70710678118654752f)));
          }
        }
        #pragma unroll
        for (int ktl = 0; ktl < 4; ++ktl) {
          short8 ahh0 = *(const short8*)(s_M + ((2 * wv + 0) * 16 + li) * 132 + ktl * 32 + lg * 8);
          short8 ahh1 = *(const short8*)(s_M + ((2 * wv + 1) * 16 + li) * 132 + ktl * 32 + lg * 8);
          #pragma unroll
          for (int nt = 0; nt < 7; ++nt) {
            short8 bw = *(const short8*)(uw + w2off + (((chunk * 4 + ktl) * 7 + nt) * 64 + lane) * 8);
            c2[0][nt] = MFMA(ahh0, bw, c2[0][nt]);
            c2[1][nt] = MFMA(ahh1, bw, c2[1][nt]);
          }
        }
      }
      {   // chunk 3: hidden 384..399
        f32x4 a0 = zero4(), a1 = zero4();
        #pragma unroll
        for (int kt = 0; kt < 4; ++kt) {
          short8 bw = *(const short8*)(uw + w1off + ((kt * 25 + 24) * 64 + lane) * 8);
          a0 = MFMA(ahm[0][kt], bw, a0);
          a1 = MFMA(ahm[1][kt], bw, a1);
        }
        const float bias = s_sm[1400 + d * 400 + 384 + li];
        #pragma unroll
        for (int rg = 0; rg < 4; ++rg) {
          const int r0 = (2 * wv) * 16 + lg * 4 + rg;
          const int r1 = (2 * wv + 1) * 16 + lg * 4 + rg;
          float h0 = a0[rg] + bias, h1 = a1[rg] + bias;
          s_M[r0 * 132 + li] = f2bf(0.5f * h0 * (1.0f + erff(h0 * 0.70710678118654752f)));
          s_M[r1 * 132 + li] = f2bf(0.5f * h1 * (1.0f + erff(h1 * 0.70710678118654752f)));
          s_M[r0 * 132 + 16 + li] = 0;
          s_M[r1 * 132 + 16 + li] = 0;
        }
        short8 ahh0 = *(const short8*)(s_M + ((2 * wv + 0) * 16 + li) * 132 + lg * 8);
        short8 ahh1 = *(const short8*)(s_M + ((2 * wv + 1) * 16 + li) * 132 + lg * 8);
        #pragma unroll
        for (int nt = 0; nt < 7; ++nt) {
          short8 bw = *(const short8*)(uw + w2off + ((12 * 7 + nt) * 64 + lane) * 8);
          c2[0][nt] = MFMA(ahh0, bw, c2[0][nt]);
          c2[1][nt] = MFMA(ahh1, bw, c2[1][nt]);
        }
      }
      #pragma unroll
      for (int mt2 = 0; mt2 < 2; ++mt2)
        #pragma unroll
        for (int nt = 0; nt < 7; ++nt) latC[mt2][nt] = c2[mt2][nt];
    }
  }

  //=================== mean over 256 latents ===================
  __syncthreads();
  #pragma unroll
  for (int nt = 0; nt < 7; ++nt) {
    float v = 0.f;
    #pragma unroll
    for (int rg = 0; rg < 4; ++rg) v += latC[0][nt][rg] + latC[1][nt][rg];
    v += __shfl_xor(v, 16);
    v += __shfl_xor(v, 32);
    if (lg == 0) Rf[wv * 112 + nt * 16 + li] = v;
  }
  __syncthreads();
  if (tid < 100) {
    float s = 0.f;
    #pragma unroll
    for (int w = 0; w < 8; ++w) s += Rf[w * 112 + tid];
    out[b * 100 + tid] = s * (1.0f / 256.0f);
  }
}

// ---------------------------------------------------------------------------
extern "C" void kernel_launch(void* const* d_in, const int* in_sizes, int n_in,
                              void* d_out, int out_size, void* d_ws, size_t ws_size,
                              hipStream_t stream) {
  (void)in_sizes; (void)n_in; (void)out_size; (void)ws_size;
  const float* x          = (const float*)d_in[0];
  const float* latents    = (const float*)d_in[1];
  const float* latent_pos = (const float*)d_in[2];
  const float* fm         = (const float*)d_in[3];
  const float* proj_w     = (const float*)d_in[4];
  const float* proj_b     = (const float*)d_in[5];
  const float* q_w        = (const float*)d_in[6];
  const float* q_b        = (const float*)d_in[7];
  const float* k_w        = (const float*)d_in[8];
  const float* k_b        = (const float*)d_in[9];
  const float* v_w        = (const float*)d_in[10];
  const float* v_b        = (const float*)d_in[11];
  const float* o_w        = (const float*)d_in[12];
  const float* o_b        = (const float*)d_in[13];
  const float* ln1_g      = (const float*)d_in[14];
  const float* ln1_b      = (const float*)d_in[15];
  const float* attn_in_w  = (const float*)d_in[16];
  const float* attn_in_b  = (const float*)d_in[17];
  const float* attn_out_w = (const float*)d_in[18];
  const float* attn_out_b = (const float*)d_in[19];
  const float* ln2_g      = (const float*)d_in[20];
  const float* ln2_b      = (const float*)d_in[21];
  const float* mlp_w1     = (const float*)d_in[22];
  const float* mlp_b1     = (const float*)d_in[23];
  const float* mlp_w2     = (const float*)d_in[24];
  const float* mlp_b2     = (const float*)d_in[25];
  float* ws   = (float*)d_ws;
  float* outp = (float*)d_out;
  unsigned short* uw = (unsigned short*)(ws + WS_U);

  pre_amat_kernel<<<3, 256, 0, stream>>>(proj_w, k_w, v_w, ws);
  pre_akt_kernel<<<8, 256, 0, stream>>>(ws, uw);
  pre_dmat_kernel<<<128, 256, 0, stream>>>(fm, proj_w, proj_b, k_w, k_b, v_w, v_b, uw);
  pre_fill_kernel<<<160, 256, 0, stream>>>(uw);
  pre_wfrag_kernel<<<(UW_WCNT + 255) / 256, 256, 0, stream>>>(
      q_w, o_w, mlp_w1, mlp_w2, attn_in_w, attn_out_w, uw);
  perceiver_kernel<<<512, 512, 0, stream>>>(
      x, latents, latent_pos, q_b, o_b,
      ln1_g, ln1_b, attn_in_b, attn_out_b,
      ln2_g, ln2_b, mlp_b1, mlp_b2, ws, outp);
}

// Round 6
// 7026.478 us; speedup vs baseline: 1.4289x; 1.4289x over previous
//
#include <hip/hip_runtime.h>
#include <cmath>

// float offsets in ws
#define WS_AK 0
#define WS_AV 300
#define WS_U  600   // ushort region starts here

// ushort offsets relative to uw = (ushort*)(ws + WS_U)
#define UW_DKT 0        // DkT B-frags [4kt][64ng][64][8]  (k=chan128, n=key1024)
#define UW_DVT 131072   // DvT B-frags [32kv][7nt][64][8]  (k=key1024, n=chan112; col100=1)
#define UW_AKT 245760   // AkT B-frags [4kt][64][8]        (k=chan128, n=16: 3 real)
#define UW_QW  247808   // q_w frags  kt4 x nt7
#define UW_OW  262144   // o_w frags  kt4 x nt7
#define UW_W1  276480   // + d*51200  kt4 x nt25
#define UW_W2  378880   // + d*50176  kt14 x nt7
#define UW_AIW 479232   // + (d*3+wsel)*16384  kt4 x nt8 (head-padded)
#define UW_AOW 577536   // + d*14336  kt4 x nt7 (head-padded k'=h*32+dh)
#define UW_WCNT 358400  // elements written by pre_wfrag (from UW_QW)

typedef __attribute__((ext_vector_type(8))) short short8;
typedef __attribute__((ext_vector_type(4))) float f32x4;

#define MFMA(a, b, c) __builtin_amdgcn_mfma_f32_16x16x32_bf16((a), (b), (c), 0, 0, 0)

static __device__ __forceinline__ unsigned short f2bf(float f) {
  unsigned int u = __float_as_uint(f);
  u += 0x7FFF + ((u >> 16) & 1);   // RNE
  return (unsigned short)(u >> 16);
}
static __device__ __forceinline__ f32x4 zero4() { return (f32x4){0.f, 0.f, 0.f, 0.f}; }

// ---------------------------------------------------------------------------
__global__ void pre_amat_kernel(const float* __restrict__ proj_w,
                                const float* __restrict__ k_w,
                                const float* __restrict__ v_w,
                                float* __restrict__ ws) {
  int idx = blockIdx.x * blockDim.x + threadIdx.x;
  if (idx >= 600) return;
  int sel = idx / 300;
  int rem = idx % 300;
  int c = rem / 100, m = rem % 100;
  const float* w = sel ? v_w : k_w;
  float acc = 0.f;
  for (int n = 0; n < 100; ++n) acc += proj_w[n * 131 + c] * w[m * 100 + n];
  ws[(sel ? WS_AV : WS_AK) + c * 100 + m] = acc;
}

// AkT frags: B[k][n] = Ak[n][k] (n<3), bf16
__global__ void pre_akt_kernel(const float* __restrict__ ws,
                               unsigned short* __restrict__ uw) {
  int idx = blockIdx.x * blockDim.x + threadIdx.x;
  if (idx >= 2048) return;
  int kt = idx >> 9, lane = (idx >> 3) & 63, j = idx & 7;
  int k = kt * 32 + (lane >> 4) * 8 + j;
  int n = lane & 15;
  float val = (k < 100 && n < 3) ? ws[WS_AK + n * 100 + k] : 0.f;
  uw[UW_AKT + idx] = f2bf(val);
}

// Zero/one pads: DkT k=100..127 -> 0 ; DvT n=100..111 -> (n==100 ? 1 : 0)
__global__ void pre_fill_kernel(unsigned short* __restrict__ uw) {
  int idx = blockIdx.x * blockDim.x + threadIdx.x;
  if (idx >= 40960) return;
  if (idx < 28672) {
    int m = 100 + idx % 28, p = idx / 28;
    int kt = m >> 5, ng = p >> 4;
    int lane = (((m & 31) >> 3) << 4) + (p & 15);
    uw[UW_DKT + ((kt * 64 + ng) * 64 + lane) * 8 + (m & 7)] = 0;
  } else {
    int r = idx - 28672;
    int m = 100 + r % 12, p = r / 12;
    int kv = p >> 5, nt = m >> 4;
    int lane = (((p & 31) >> 3) << 4) + (m & 15);
    uw[UW_DVT + ((kv * 7 + nt) * 64 + lane) * 8 + (p & 7)] =
        (m == 100) ? (unsigned short)0x3F80 : (unsigned short)0;
  }
}

// ---------------------------------------------------------------------------
// Dk/Dv (batch-independent K/V parts) straight into B-frag layouts (bf16)
// ---------------------------------------------------------------------------
__global__ void pre_dmat_kernel(const float* __restrict__ fm,
                                const float* __restrict__ proj_w,
                                const float* __restrict__ proj_b,
                                const float* __restrict__ k_w,
                                const float* __restrict__ k_b,
                                const float* __restrict__ v_w,
                                const float* __restrict__ v_b,
                                unsigned short* __restrict__ uw) {
  __shared__ float pos[8][128];
  __shared__ float tc[8][100];
  int p0 = blockIdx.x * 8;
  int tid = threadIdx.x;
  for (int idx = tid; idx < 1024; idx += 256) {
    int pl = idx >> 7, f = idx & 127;
    int p = p0 + pl;
    float cx = (float)(p & 31) * (1.f / 31.f);
    float cy = (float)(p >> 5) * (1.f / 31.f);
    int fi = f & 63;
    float pr = cx * fm[fi] + cy * fm[64 + fi];
    float ang = 6.2831853071795864769f * pr;
    pos[pl][f] = (f < 64) ? cosf(ang) : sinf(ang);
  }
  __syncthreads();
  for (int idx = tid; idx < 800; idx += 256) {
    int pl = idx / 100, n = idx % 100;
    float acc = proj_b[n];
    const float* pw = proj_w + n * 131 + 3;
    for (int f = 0; f < 128; ++f) acc += pos[pl][f] * pw[f];
    tc[pl][n] = acc;
  }
  __syncthreads();
  for (int idx = tid; idx < 1600; idx += 256) {
    int sel = idx / 800;
    int rem = idx % 800;
    int pl = rem / 100, m = rem % 100;
    int p = p0 + pl;
    const float* w = sel ? v_w : k_w;
    float acc = sel ? v_b[m] : k_b[m];
    for (int n = 0; n < 100; ++n) acc += tc[pl][n] * w[m * 100 + n];
    if (sel) {   // DvT: k=key p, n=chan m
      int kv = p >> 5, nt = m >> 4;
      int lane = (((p & 31) >> 3) << 4) + (m & 15);
      uw[UW_DVT + ((kv * 7 + nt) * 64 + lane) * 8 + (p & 7)] = f2bf(acc);
    } else {     // DkT: k=chan m, n=key p
      int kt = m >> 5, ng = p >> 4;
      int lane = (((m & 31) >> 3) << 4) + (p & 15);
      uw[UW_DKT + ((kt * 64 + ng) * 64 + lane) * 8 + (m & 7)] = f2bf(acc);
    }
  }
}

// ---------------------------------------------------------------------------
__global__ void pre_wfrag_kernel(const float* __restrict__ q_w,
                                 const float* __restrict__ o_w,
                                 const float* __restrict__ mlp_w1,
                                 const float* __restrict__ mlp_w2,
                                 const float* __restrict__ attn_in_w,
                                 const float* __restrict__ attn_out_w,
                                 unsigned short* __restrict__ uw) {
  int idx = blockIdx.x * 256 + threadIdx.x;
  if (idx >= UW_WCNT) return;
  float val = 0.f;
  if (idx < 14336) {
    int rem = idx;
    int kt = rem / 3584; rem %= 3584;
    int nt = rem / 512;  rem %= 512;
    int lane = rem >> 3, j = rem & 7;
    int k = kt * 32 + (lane >> 4) * 8 + j;
    int n = nt * 16 + (lane & 15);
    if (k < 100 && n < 100) val = q_w[n * 100 + k];
  } else if (idx < 28672) {
    int rem = idx - 14336;
    int kt = rem / 3584; rem %= 3584;
    int nt = rem / 512;  rem %= 512;
    int lane = rem >> 3, j = rem & 7;
    int k = kt * 32 + (lane >> 4) * 8 + j;
    int n = nt * 16 + (lane & 15);
    if (k < 100 && n < 100) val = o_w[n * 100 + k];
  } else if (idx < 131072) {
    int off = idx - 28672;
    int dd = off / 51200;
    int rem = off % 51200;
    int kt = rem / 12800; rem %= 12800;
    int nt = rem / 512;   rem %= 512;
    int lane = rem >> 3, j = rem & 7;
    int k = kt * 32 + (lane >> 4) * 8 + j;
    int n = nt * 16 + (lane & 15);
    if (k < 100) val = mlp_w1[dd * 40000 + n * 100 + k];
  } else if (idx < 231424) {
    int off = idx - 131072;
    int dd = off / 50176;
    int rem = off % 50176;
    int kt = rem / 3584; rem %= 3584;
    int nt = rem / 512;  rem %= 512;
    int lane = rem >> 3, j = rem & 7;
    int k = kt * 32 + (lane >> 4) * 8 + j;
    int n = nt * 16 + (lane & 15);
    if (k < 400 && n < 100) val = mlp_w2[dd * 40000 + n * 400 + k];
  } else if (idx < 329728) {
    int off = idx - 231424;
    int dw = off / 16384;
    int rem = off % 16384;
    int dd = dw / 3, wsel = dw % 3;
    int kt = rem / 4096; rem %= 4096;
    int nt = rem / 512;  rem %= 512;
    int lane = rem >> 3, j = rem & 7;
    int k = kt * 32 + (lane >> 4) * 8 + j;
    int np = nt * 16 + (lane & 15);
    int hh = np >> 5, dh = np & 31;
    if (k < 100 && dh < 25)
      val = attn_in_w[dd * 30000 + (wsel * 100 + hh * 25 + dh) * 100 + k];
  } else {
    int off = idx - 329728;
    int dd = off / 14336;
    int rem = off % 14336;
    int kt = rem / 3584; rem %= 3584;
    int nt = rem / 512;  rem %= 512;
    int lane = rem >> 3, j = rem & 7;
    int kp = kt * 32 + (lane >> 4) * 8 + j;
    int hh = kp >> 5, dh = kp & 31;
    int n = nt * 16 + (lane & 15);
    if (dh < 25 && n < 100)
      val = attn_out_w[dd * 10000 + n * 100 + hh * 25 + dh];
  }
  uw[UW_QW + idx] = f2bf(val);
}

// ---------------------------------------------------------------------------
// Main kernel: 1 block/batch, 512 threads (8 waves), 2 blocks/CU (80 KB LDS,
// 128 VGPR). Residual lat in MFMA C-layout f32 regs latC[mt2][nt][rg].
// Cross-attn: two per-m-tile passes, each register-bounded (~100 VGPR peak):
//   S = q.DkT (global frags) + rank-3 x-correction (VALU),
//   O = P.DvT (global frags) + pxa.Av fixup; P scratch is wave-private LDS.
// Tile loop has 0 barriers.
// ---------------------------------------------------------------------------
__launch_bounds__(512, 2)
__global__ void perceiver_kernel(
    const float* __restrict__ x,
    const float* __restrict__ latents,
    const float* __restrict__ latent_pos,
    const float* __restrict__ q_b, const float* __restrict__ o_b,
    const float* __restrict__ ln1_g, const float* __restrict__ ln1_b,
    const float* __restrict__ attn_in_b, const float* __restrict__ attn_out_b,
    const float* __restrict__ ln2_g, const float* __restrict__ ln2_b,
    const float* __restrict__ mlp_b1, const float* __restrict__ mlp_b2,
    const float* __restrict__ ws,
    float* __restrict__ out) {
  __shared__ __align__(16) float s_pool[19908];
  float* s_sm = s_pool;                        // 2500 floats
  float* Rf   = s_pool + 2500;                 // 17408 floats = 34816 ushorts
  unsigned short* R   = (unsigned short*)Rf;
  unsigned short* s_M = R;                     // [256][132] bf16 staging
  // MHA aliases
  unsigned short* sQh   = R;                   // [256][36]
  unsigned short* kfrag = R + 9216;            // 8192
  unsigned short* vfrag = R + 17408;           // 8192
  unsigned short* sPm   = R + 25600;           // [256][36]

  const int tid  = threadIdx.x;
  const int b    = blockIdx.x;
  const int lane = tid & 63;
  const int wv   = tid >> 6;
  const int li   = lane & 15;
  const int lg   = lane >> 4;
  const unsigned short* uw = (const unsigned short*)(ws + WS_U);
  // wave-private P scratch [16][76] inside own slice's tile-1 row region
  unsigned short* spw = R + wv * 4224 + 2112;

  // ---- stage hot constants ----
  for (int i = tid; i < 200; i += 512) {
    s_sm[i] = ln1_g[i]; s_sm[200 + i] = ln1_b[i];
    s_sm[400 + i] = ln2_g[i]; s_sm[600 + i] = ln2_b[i];
  }
  for (int i = tid; i < 600; i += 512) s_sm[800 + i] = attn_in_b[i];
  for (int i = tid; i < 800; i += 512) s_sm[1400 + i] = mlp_b1[i];
  for (int i = tid; i < 300; i += 512) s_sm[2200 + i] = ws[WS_AV + i];
  __syncthreads();

  // ---- residual in C-layout regs ----
  f32x4 latC[2][7];
  #pragma unroll
  for (int mt2 = 0; mt2 < 2; ++mt2)
    #pragma unroll
    for (int nt = 0; nt < 7; ++nt) {
      const int col = nt * 16 + li;
      #pragma unroll
      for (int rg = 0; rg < 4; ++rg) {
        const int row = (2 * wv + mt2) * 16 + lg * 4 + rg;
        latC[mt2][nt][rg] = (col < 100)
            ? latents[row * 100 + col] + latent_pos[row * 100 + col] : 0.f;
      }
    }

  const float* xb = x + (long)b * 3072;

  // LN helper: latC -> s_M (bf16, zero-padded cols 100..127)
  auto ln_stage = [&](const float* gg, const float* bb) {
    #pragma unroll
    for (int mt2 = 0; mt2 < 2; ++mt2)
      #pragma unroll
      for (int rg = 0; rg < 4; ++rg) {
        float s = 0.f, sq = 0.f;
        #pragma unroll
        for (int nt = 0; nt < 7; ++nt) {
          const int col = nt * 16 + li;
          if (col < 100) { const float v = latC[mt2][nt][rg]; s += v; sq += v * v; }
        }
        s += __shfl_xor(s, 1); sq += __shfl_xor(sq, 1);
        s += __shfl_xor(s, 2); sq += __shfl_xor(sq, 2);
        s += __shfl_xor(s, 4); sq += __shfl_xor(sq, 4);
        s += __shfl_xor(s, 8); sq += __shfl_xor(sq, 8);
        const float mu = s * 0.01f;
        const float rs = rsqrtf(sq * 0.01f - mu * mu + 1e-5f);
        const int row = (2 * wv + mt2) * 16 + lg * 4 + rg;
        #pragma unroll
        for (int nt = 0; nt < 7; ++nt) {
          const int col = nt * 16 + li;
          s_M[row * 132 + col] = (col < 100)
              ? f2bf((latC[mt2][nt][rg] - mu) * rs * gg[col] + bb[col]) : 0;
        }
        s_M[row * 132 + 112 + li] = 0;
      }
  };

  // One per-m-tile cross-attn pass: tile loop + fixups + normalize + o-proj.
  // aqp: q A-frags (4), qav: qa C-layout acc, latCp: output row, rowbase.
  auto cross_pass = [&](const short8* aqp, f32x4 qav, f32x4* latCp, int rowbase) {
    // qa3 broadcast (tile-invariant)
    float qa3[4][3];
    #pragma unroll
    for (int rg = 0; rg < 4; ++rg)
      #pragma unroll
      for (int ch = 0; ch < 3; ++ch)
        qa3[rg][ch] = __shfl(qav[rg], (lane & 48) + ch);

    f32x4 O7[7];
    #pragma unroll
    for (int nt = 0; nt < 7; ++nt) O7[nt] = zero4();
    float pxa[4][3];
    #pragma unroll
    for (int rg = 0; rg < 4; ++rg)
      #pragma unroll
      for (int ch = 0; ch < 3; ++ch) pxa[rg][ch] = 0.f;

    for (int t0 = 0; t0 < 1024; t0 += 64) {
      // S + exp + pxa + P-stage per ntk
      #pragma unroll
      for (int ntk = 0; ntk < 4; ++ntk) {
        f32x4 s0 = zero4();
        #pragma unroll
        for (int kt = 0; kt < 4; ++kt) {
          short8 bk = *(const short8*)(uw + UW_DKT + ((kt * 64 + (t0 >> 4) + ntk) * 64 + lane) * 8);
          s0 = MFMA(aqp[kt], bk, s0);
        }
        const int p = t0 + ntk * 16 + li;
        const float xr = xb[p], xg = xb[1024 + p], xv = xb[2048 + p];
        #pragma unroll
        for (int rg = 0; rg < 4; ++rg) {
          float sv = s0[rg] + qa3[rg][0] * xr + qa3[rg][1] * xg + qa3[rg][2] * xv;
          float pe = __expf(sv);
          pxa[rg][0] += pe * xr; pxa[rg][1] += pe * xg; pxa[rg][2] += pe * xv;
          spw[(lg * 4 + rg) * 76 + ntk * 16 + li] = f2bf(pe);
        }
      }
      // PV vs global DvT frags
      short8 ap0 = *(const short8*)(spw + li * 76 + lg * 8);
      short8 ap1 = *(const short8*)(spw + li * 76 + 32 + lg * 8);
      const int kv = t0 >> 5;
      #pragma unroll
      for (int nt = 0; nt < 7; ++nt) {
        short8 bv0 = *(const short8*)(uw + UW_DVT + ((kv * 7 + nt) * 64 + lane) * 8);
        short8 bv1 = *(const short8*)(uw + UW_DVT + (((kv + 1) * 7 + nt) * 64 + lane) * 8);
        O7[nt] = MFMA(ap0, bv0, O7[nt]);
        O7[nt] = MFMA(ap1, bv1, O7[nt]);
      }
    }

    // reduce pxa over 16-lane key groups
    #pragma unroll
    for (int rg = 0; rg < 4; ++rg)
      #pragma unroll
      for (int ch = 0; ch < 3; ++ch) {
        float v = pxa[rg][ch];
        v += __shfl_xor(v, 1);
        v += __shfl_xor(v, 2);
        v += __shfl_xor(v, 4);
        v += __shfl_xor(v, 8);
        pxa[rg][ch] = v;
      }
    // O += pxa . Av (cols < 100; col 100 (=l) untouched)
    #pragma unroll
    for (int nt = 0; nt < 7; ++nt) {
      const int col = nt * 16 + li;
      if (col < 100) {
        const float av0 = s_sm[2200 + col], av1 = s_sm[2300 + col], av2 = s_sm[2400 + col];
        #pragma unroll
        for (int rg = 0; rg < 4; ++rg)
          O7[nt][rg] += pxa[rg][0] * av0 + pxa[rg][1] * av1 + pxa[rg][2] * av2;
      }
    }
    // normalize (l at col 100 -> nt=6, li==4), write o_in -> s_M rows
    #pragma unroll
    for (int rg = 0; rg < 4; ++rg) {
      const float lv = __shfl(O7[6][rg], (lane & 48) + 4);
      const float linv = 1.0f / lv;
      const int row = rowbase + lg * 4 + rg;
      #pragma unroll
      for (int nt = 0; nt < 7; ++nt) {
        const int col = nt * 16 + li;
        s_M[row * 132 + col] = (col < 100) ? f2bf(O7[nt][rg] * linv) : 0;
      }
      s_M[row * 132 + 112 + li] = 0;
    }
    // o-proj for this tile -> latCp
    short8 ao[4];
    #pragma unroll
    for (int kt = 0; kt < 4; ++kt)
      ao[kt] = *(const short8*)(s_M + (rowbase + li) * 132 + kt * 32 + lg * 8);
    #pragma unroll
    for (int nt = 0; nt < 7; ++nt) {
      f32x4 a0 = zero4();
      #pragma unroll
      for (int kt = 0; kt < 4; ++kt) {
        short8 bw = *(const short8*)(uw + UW_OW + ((kt * 7 + nt) * 64 + lane) * 8);
        a0 = MFMA(ao[kt], bw, a0);
      }
      const int col = nt * 16 + li;
      const float ob = (col < 100) ? o_b[col] : 0.f;
      #pragma unroll
      for (int rg = 0; rg < 4; ++rg)
        latCp[nt][rg] = (col < 100) ? a0[rg] + ob : 0.f;
    }
  };

  for (int it = 0; it < 8; ++it) {
    //=================== cross attention (barrier-free) ===================
    // stage lat -> s_M (own rows)
    #pragma unroll
    for (int mt2 = 0; mt2 < 2; ++mt2)
      #pragma unroll
      for (int rg = 0; rg < 4; ++rg) {
        const int row = (2 * wv + mt2) * 16 + lg * 4 + rg;
        #pragma unroll
        for (int nt = 0; nt < 7; ++nt) {
          const int col = nt * 16 + li;
          s_M[row * 132 + col] = (col < 100) ? f2bf(latC[mt2][nt][rg]) : 0;
        }
        s_M[row * 132 + 112 + li] = 0;
      }

    // q-proj: q_s = (lat @ q_w^T + q_b) * 0.1 -> s_M (own rows)
    {
      short8 aq[2][4];
      #pragma unroll
      for (int mt2 = 0; mt2 < 2; ++mt2)
        #pragma unroll
        for (int kt = 0; kt < 4; ++kt)
          aq[mt2][kt] = *(const short8*)(s_M + ((2 * wv + mt2) * 16 + li) * 132 + kt * 32 + lg * 8);
      #pragma unroll
      for (int nt = 0; nt < 7; ++nt) {
        f32x4 a0 = zero4(), a1 = zero4();
        #pragma unroll
        for (int kt = 0; kt < 4; ++kt) {
          short8 bw = *(const short8*)(uw + UW_QW + ((kt * 7 + nt) * 64 + lane) * 8);
          a0 = MFMA(aq[0][kt], bw, a0);
          a1 = MFMA(aq[1][kt], bw, a1);
        }
        const int col = nt * 16 + li;
        const float qb = (col < 100) ? q_b[col] : 0.f;
        #pragma unroll
        for (int rg = 0; rg < 4; ++rg) {
          const int r0 = (2 * wv) * 16 + lg * 4 + rg;
          const int r1 = (2 * wv + 1) * 16 + lg * 4 + rg;
          s_M[r0 * 132 + col] = (col < 100) ? f2bf((a0[rg] + qb) * 0.1f) : 0;
          s_M[r1 * 132 + col] = (col < 100) ? f2bf((a1[rg] + qb) * 0.1f) : 0;
        }
      }
    }

    // q A-frags for BOTH tiles (pass 0 scribbles tile-1 rows as P scratch)
    short8 aq2[2][4];
    #pragma unroll
    for (int mt2 = 0; mt2 < 2; ++mt2)
      #pragma unroll
      for (int kt = 0; kt < 4; ++kt)
        aq2[mt2][kt] = *(const short8*)(s_M + ((2 * wv + mt2) * 16 + li) * 132 + kt * 32 + lg * 8);

    // qa = q_s . Ak^T  (C-layout, cols 0..2 valid)
    f32x4 qa0v = zero4(), qa1v = zero4();
    #pragma unroll
    for (int kt = 0; kt < 4; ++kt) {
      short8 bw = *(const short8*)(uw + UW_AKT + (kt * 64 + lane) * 8);
      qa0v = MFMA(aq2[0][kt], bw, qa0v);
      qa1v = MFMA(aq2[1][kt], bw, qa1v);
    }

    cross_pass(aq2[0], qa0v, latC[0], (2 * wv) * 16);
    cross_pass(aq2[1], qa1v, latC[1], (2 * wv + 1) * 16);

    //=================== latent transformer ===================
    for (int d = 0; d < 2; ++d) {
      // ---- LN1 -> s_M (own rows)
      ln_stage(&s_sm[d * 100], &s_sm[200 + d * 100]);
      short8 ah[2][4];
      #pragma unroll
      for (int mt2 = 0; mt2 < 2; ++mt2)
        #pragma unroll
        for (int kt = 0; kt < 4; ++kt)
          ah[mt2][kt] = *(const short8*)(s_M + ((2 * wv + mt2) * 16 + li) * 132 + kt * 32 + lg * 8);

      // co init = lat + attn_out_b
      f32x4 co[2][7];
      #pragma unroll
      for (int nt = 0; nt < 7; ++nt) {
        const int col = nt * 16 + li;
        const float ob = (col < 100) ? attn_out_b[d * 100 + col] : 0.f;
        #pragma unroll
        for (int rg = 0; rg < 4; ++rg) {
          co[0][nt][rg] = (col < 100) ? latC[0][nt][rg] + ob : 0.f;
          co[1][nt][rg] = (col < 100) ? latC[1][nt][rg] + ob : 0.f;
        }
      }

      for (int h = 0; h < 4; ++h) {
        __syncthreads();   // prior reads of R complete before scratch writes
        #pragma unroll
        for (int ntd = 0; ntd < 2; ++ntd) {
          f32x4 cq0 = zero4(), cq1 = zero4(), ck0 = zero4(), ck1 = zero4(),
                cv0 = zero4(), cv1 = zero4();
          #pragma unroll
          for (int kt = 0; kt < 4; ++kt) {
            const int bidx = ((kt * 8 + h * 2 + ntd) * 64 + lane) * 8;
            short8 bq  = *(const short8*)(uw + UW_AIW + (d * 3 + 0) * 16384 + bidx);
            short8 bkk = *(const short8*)(uw + UW_AIW + (d * 3 + 1) * 16384 + bidx);
            short8 bvv = *(const short8*)(uw + UW_AIW + (d * 3 + 2) * 16384 + bidx);
            cq0 = MFMA(ah[0][kt], bq,  cq0); cq1 = MFMA(ah[1][kt], bq,  cq1);
            ck0 = MFMA(ah[0][kt], bkk, ck0); ck1 = MFMA(ah[1][kt], bkk, ck1);
            cv0 = MFMA(ah[0][kt], bvv, cv0); cv1 = MFMA(ah[1][kt], bvv, cv1);
          }
          const int dh = ntd * 16 + li;
          const bool ok = dh < 25;
          const float qb2 = ok ? s_sm[800 + d * 300 +       h * 25 + dh] : 0.f;
          const float kb2 = ok ? s_sm[800 + d * 300 + 100 + h * 25 + dh] : 0.f;
          const float vb2 = ok ? s_sm[800 + d * 300 + 200 + h * 25 + dh] : 0.f;
          #pragma unroll
          for (int mt2 = 0; mt2 < 2; ++mt2)
            #pragma unroll
            for (int rg = 0; rg < 4; ++rg) {
              const int rr = lg * 4 + rg;
              const int row = (2 * wv + mt2) * 16 + rr;
              const float q = mt2 ? cq1[rg] : cq0[rg];
              const float k = mt2 ? ck1[rg] : ck0[rg];
              const float v = mt2 ? cv1[rg] : cv0[rg];
              sQh[row * 36 + dh] = ok ? f2bf((q + qb2) * 0.2f) : 0;
              kfrag[((2 * wv + mt2) * 64 + (dh >> 3) * 16 + rr) * 8 + (dh & 7)] =
                  ok ? f2bf(k + kb2) : 0;
              vfrag[((wv * 2 + ntd) * 64 + (mt2 * 2 + (rr >> 3)) * 16 + li) * 8 + (rr & 7)] =
                  ok ? f2bf(v + vb2) : (unsigned short)((dh == 25) ? 0x3F80 : 0);
            }
        }
        __syncthreads();   // kfrag/vfrag visible

        short8 aqh0 = *(const short8*)(sQh + ((2 * wv + 0) * 16 + li) * 36 + lg * 8);
        short8 aqh1 = *(const short8*)(sQh + ((2 * wv + 1) * 16 + li) * 36 + lg * 8);
        f32x4 Oh00 = zero4(), Oh01 = zero4(), Oh10 = zero4(), Oh11 = zero4();
        for (int t = 0; t < 8; ++t) {
          short8 bk0 = *(const short8*)(kfrag + ((t * 2 + 0) * 64 + lane) * 8);
          short8 bk1 = *(const short8*)(kfrag + ((t * 2 + 1) * 64 + lane) * 8);
          f32x4 s00 = MFMA(aqh0, bk0, zero4());
          f32x4 s01 = MFMA(aqh0, bk1, zero4());
          f32x4 s10 = MFMA(aqh1, bk0, zero4());
          f32x4 s11 = MFMA(aqh1, bk1, zero4());
          #pragma unroll
          for (int rg = 0; rg < 4; ++rg) {
            const int r0 = (2 * wv) * 16 + lg * 4 + rg;
            const int r1 = (2 * wv + 1) * 16 + lg * 4 + rg;
            sPm[r0 * 36 + li]      = f2bf(__expf(s00[rg]));
            sPm[r0 * 36 + 16 + li] = f2bf(__expf(s01[rg]));
            sPm[r1 * 36 + li]      = f2bf(__expf(s10[rg]));
            sPm[r1 * 36 + 16 + li] = f2bf(__expf(s11[rg]));
          }
          short8 ap0 = *(const short8*)(sPm + ((2 * wv + 0) * 16 + li) * 36 + lg * 8);
          short8 ap1 = *(const short8*)(sPm + ((2 * wv + 1) * 16 + li) * 36 + lg * 8);
          short8 bv0 = *(const short8*)(vfrag + ((t * 2 + 0) * 64 + lane) * 8);
          short8 bv1 = *(const short8*)(vfrag + ((t * 2 + 1) * 64 + lane) * 8);
          Oh00 = MFMA(ap0, bv0, Oh00); Oh01 = MFMA(ap0, bv1, Oh01);
          Oh10 = MFMA(ap1, bv0, Oh10); Oh11 = MFMA(ap1, bv1, Oh11);
        }
        #pragma unroll
        for (int mt2 = 0; mt2 < 2; ++mt2)
          #pragma unroll
          for (int rg = 0; rg < 4; ++rg) {
            const f32x4& o0 = mt2 ? Oh10 : Oh00;
            const f32x4& o1 = mt2 ? Oh11 : Oh01;
            const float lv = __shfl(o1[rg], (lane & 48) + 9);
            const float linv = 1.0f / lv;
            const int row = (2 * wv + mt2) * 16 + lg * 4 + rg;
            sPm[row * 36 + li]      = (li < 25)      ? f2bf(o0[rg] * linv) : 0;
            sPm[row * 36 + 16 + li] = (16 + li < 25) ? f2bf(o1[rg] * linv) : 0;
          }
        short8 ao0 = *(const short8*)(sPm + ((2 * wv + 0) * 16 + li) * 36 + lg * 8);
        short8 ao1 = *(const short8*)(sPm + ((2 * wv + 1) * 16 + li) * 36 + lg * 8);
        #pragma unroll
        for (int nt = 0; nt < 7; ++nt) {
          short8 bw = *(const short8*)(uw + UW_AOW + d * 14336 + ((h * 7 + nt) * 64 + lane) * 8);
          co[0][nt] = MFMA(ao0, bw, co[0][nt]);
          co[1][nt] = MFMA(ao1, bw, co[1][nt]);
        }
      }
      __syncthreads();   // all scratch reads done

      #pragma unroll
      for (int mt2 = 0; mt2 < 2; ++mt2)
        #pragma unroll
        for (int nt = 0; nt < 7; ++nt) latC[mt2][nt] = co[mt2][nt];

      // ---- LN2 -> s_M, MLP
      ln_stage(&s_sm[400 + d * 100], &s_sm[600 + d * 100]);
      short8 ahm[2][4];
      #pragma unroll
      for (int mt2 = 0; mt2 < 2; ++mt2)
        #pragma unroll
        for (int kt = 0; kt < 4; ++kt)
          ahm[mt2][kt] = *(const short8*)(s_M + ((2 * wv + mt2) * 16 + li) * 132 + kt * 32 + lg * 8);

      f32x4 c2[2][7];
      #pragma unroll
      for (int nt = 0; nt < 7; ++nt) {
        const int col = nt * 16 + li;
        const float b2 = (col < 100) ? mlp_b2[d * 100 + col] : 0.f;
        #pragma unroll
        for (int rg = 0; rg < 4; ++rg) {
          c2[0][nt][rg] = (col < 100) ? latC[0][nt][rg] + b2 : 0.f;
          c2[1][nt][rg] = (col < 100) ? latC[1][nt][rg] + b2 : 0.f;
        }
      }

      const int w1off = UW_W1 + d * 51200;
      const int w2off = UW_W2 + d * 50176;
      for (int chunk = 0; chunk < 3; ++chunk) {
        #pragma unroll
        for (int ntl = 0; ntl < 8; ++ntl) {
          f32x4 a0 = zero4(), a1 = zero4();
          #pragma unroll
          for (int kt = 0; kt < 4; ++kt) {
            short8 bw = *(const short8*)(uw + w1off + ((kt * 25 + (chunk * 8 + ntl)) * 64 + lane) * 8);
            a0 = MFMA(ahm[0][kt], bw, a0);
            a1 = MFMA(ahm[1][kt], bw, a1);
          }
          const int col = ntl * 16 + li;
          const float bias = s_sm[1400 + d * 400 + chunk * 128 + col];
          #pragma unroll
          for (int rg = 0; rg < 4; ++rg) {
            const int r0 = (2 * wv) * 16 + lg * 4 + rg;
            const int r1 = (2 * wv + 1) * 16 + lg * 4 + rg;
            float h0 = a0[rg] + bias, h1 = a1[rg] + bias;
            s_M[r0 * 132 + col] = f2bf(0.5f * h0 * (1.0f + erff(h0 * 0.70710678118654752f)));
            s_M[r1 * 132 + col] = f2bf(0.5f * h1 * (1.0f + erff(h1 * 0.70710678118654752f)));
          }
        }
        #pragma unroll
        for (int ktl = 0; ktl < 4; ++ktl) {
          short8 ahh0 = *(const short8*)(s_M + ((2 * wv + 0) * 16 + li) * 132 + ktl * 32 + lg * 8);
          short8 ahh1 = *(const short8*)(s_M + ((2 * wv + 1) * 16 + li) * 132 + ktl * 32 + lg * 8);
          #pragma unroll
          for (int nt = 0; nt < 7; ++nt) {
            short8 bw = *(const short8*)(uw + w2off + (((chunk * 4 + ktl) * 7 + nt) * 64 + lane) * 8);
            c2[0][nt] = MFMA(ahh0, bw, c2[0][nt]);
            c2[1][nt] = MFMA(ahh1, bw, c2[1][nt]);
          }
        }
      }
      {   // chunk 3: hidden 384..399
        f32x4 a0 = zero4(), a1 = zero4();
        #pragma unroll
        for (int kt = 0; kt < 4; ++kt) {
          short8 bw = *(const short8*)(uw + w1off + ((kt * 25 + 24) * 64 + lane) * 8);
          a0 = MFMA(ahm[0][kt], bw, a0);
          a1 = MFMA(ahm[1][kt], bw, a1);
        }
        const float bias = s_sm[1400 + d * 400 + 384 + li];
        #pragma unroll
        for (int rg = 0; rg < 4; ++rg) {
          const int r0 = (2 * wv) * 16 + lg * 4 + rg;
          const int r1 = (2 * wv + 1) * 16 + lg * 4 + rg;
          float h0 = a0[rg] + bias, h1 = a1[rg] + bias;
          s_M[r0 * 132 + li] = f2bf(0.5f * h0 * (1.0f + erff(h0 * 0.70710678118654752f)));
          s_M[r1 * 132 + li] = f2bf(0.5f * h1 * (1.0f + erff(h1 * 0.70710678118654752f)));
          s_M[r0 * 132 + 16 + li] = 0;
          s_M[r1 * 132 + 16 + li] = 0;
        }
        short8 ahh0 = *(const short8*)(s_M + ((2 * wv + 0) * 16 + li) * 132 + lg * 8);
        short8 ahh1 = *(const short8*)(s_M + ((2 * wv + 1) * 16 + li) * 132 + lg * 8);
        #pragma unroll
        for (int nt = 0; nt < 7; ++nt) {
          short8 bw = *(const short8*)(uw + w2off + ((12 * 7 + nt) * 64 + lane) * 8);
          c2[0][nt] = MFMA(ahh0, bw, c2[0][nt]);
          c2[1][nt] = MFMA(ahh1, bw, c2[1][nt]);
        }
      }
      #pragma unroll
      for (int mt2 = 0; mt2 < 2; ++mt2)
        #pragma unroll
        for (int nt = 0; nt < 7; ++nt) latC[mt2][nt] = c2[mt2][nt];
    }
  }

  //=================== mean over 256 latents ===================
  __syncthreads();
  #pragma unroll
  for (int nt = 0; nt < 7; ++nt) {
    float v = 0.f;
    #pragma unroll
    for (int rg = 0; rg < 4; ++rg) v += latC[0][nt][rg] + latC[1][nt][rg];
    v += __shfl_xor(v, 16);
    v += __shfl_xor(v, 32);
    if (lg == 0) Rf[wv * 112 + nt * 16 + li] = v;
  }
  __syncthreads();
  if (tid < 100) {
    float s = 0.f;
    #pragma unroll
    for (int w = 0; w < 8; ++w) s += Rf[w * 112 + tid];
    out[b * 100 + tid] = s * (1.0f / 256.0f);
  }
}

// ---------------------------------------------------------------------------
extern "C" void kernel_launch(void* const* d_in, const int* in_sizes, int n_in,
                              void* d_out, int out_size, void* d_ws, size_t ws_size,
                              hipStream_t stream) {
  (void)in_sizes; (void)n_in; (void)out_size; (void)ws_size;
  const float* x          = (const float*)d_in[0];
  const float* latents    = (const float*)d_in[1];
  const float* latent_pos = (const float*)d_in[2];
  const float* fm         = (const float*)d_in[3];
  const float* proj_w     = (const float*)d_in[4];
  const float* proj_b     = (const float*)d_in[5];
  const float* q_w        = (const float*)d_in[6];
  const float* q_b        = (const float*)d_in[7];
  const float* k_w        = (const float*)d_in[8];
  const float* k_b        = (const float*)d_in[9];
  const float* v_w        = (const float*)d_in[10];
  const float* v_b        = (const float*)d_in[11];
  const float* o_w        = (const float*)d_in[12];
  const float* o_b        = (const float*)d_in[13];
  const float* ln1_g      = (const float*)d_in[14];
  const float* ln1_b      = (const float*)d_in[15];
  const float* attn_in_w  = (const float*)d_in[16];
  const float* attn_in_b  = (const float*)d_in[17];
  const float* attn_out_w = (const float*)d_in[18];
  const float* attn_out_b = (const float*)d_in[19];
  const float* ln2_g      = (const float*)d_in[20];
  const float* ln2_b      = (const float*)d_in[21];
  const float* mlp_w1     = (const float*)d_in[22];
  const float* mlp_b1     = (const float*)d_in[23];
  const float* mlp_w2     = (const float*)d_in[24];
  const float* mlp_b2     = (const float*)d_in[25];
  float* ws   = (float*)d_ws;
  float* outp = (float*)d_out;
  unsigned short* uw = (unsigned short*)(ws + WS_U);

  pre_amat_kernel<<<3, 256, 0, stream>>>(proj_w, k_w, v_w, ws);
  pre_akt_kernel<<<8, 256, 0, stream>>>(ws, uw);
  pre_dmat_kernel<<<128, 256, 0, stream>>>(fm, proj_w, proj_b, k_w, k_b, v_w, v_b, uw);
  pre_fill_kernel<<<160, 256, 0, stream>>>(uw);
  pre_wfrag_kernel<<<(UW_WCNT + 255) / 256, 256, 0, stream>>>(
      q_w, o_w, mlp_w1, mlp_w2, attn_in_w, attn_out_w, uw);
  perceiver_kernel<<<512, 512, 0, stream>>>(
      x, latents, latent_pos, q_b, o_b,
      ln1_g, ln1_b, attn_in_b, attn_out_b,
      ln2_g, ln2_b, mlp_b1, mlp_b2, ws, outp);
}

// Round 8
// 6740.116 us; speedup vs baseline: 1.4896x; 1.0425x over previous
//
#include <hip/hip_runtime.h>
#include <cmath>

// float offsets in ws
#define WS_AK 0
#define WS_AV 300
#define WS_U  600   // ushort region starts here

// ushort offsets relative to uw = (ushort*)(ws + WS_U)
#define UW_DKT 0        // DkT B-frags [4kt][64ng][64][8]  (k=chan128, n=key1024)
#define UW_DVT 131072   // DvT B-frags [32kv][7nt][64][8]  (k=key1024, n=chan112; col100=1)
#define UW_AKT 245760   // AkT B-frags [4kt][64][8]        (k=chan128, n=16: 3 real)
#define UW_QW  247808   // q_w frags  kt4 x nt7
#define UW_OW  262144   // o_w frags  kt4 x nt7
#define UW_W1  276480   // + d*51200  kt4 x nt25
#define UW_W2  378880   // + d*50176  kt14 x nt7
#define UW_AIW 479232   // + (d*3+wsel)*16384  kt4 x nt8 (head-padded)
#define UW_AOW 577536   // + d*14336  kt4 x nt7 (head-padded k'=h*32+dh)
#define UW_WCNT 358400  // elements written by pre_wfrag (from UW_QW)

typedef __attribute__((ext_vector_type(8))) short short8;
typedef __attribute__((ext_vector_type(4))) float f32x4;

#define MFMA(a, b, c) __builtin_amdgcn_mfma_f32_16x16x32_bf16((a), (b), (c), 0, 0, 0)

static __device__ __forceinline__ unsigned short f2bf(float f) {
  unsigned int u = __float_as_uint(f);
  u += 0x7FFF + ((u >> 16) & 1);   // RNE
  return (unsigned short)(u >> 16);
}
static __device__ __forceinline__ f32x4 zero4() { return (f32x4){0.f, 0.f, 0.f, 0.f}; }

// ---------------------------------------------------------------------------
__global__ void pre_amat_kernel(const float* __restrict__ proj_w,
                                const float* __restrict__ k_w,
                                const float* __restrict__ v_w,
                                float* __restrict__ ws) {
  int idx = blockIdx.x * blockDim.x + threadIdx.x;
  if (idx >= 600) return;
  int sel = idx / 300;
  int rem = idx % 300;
  int c = rem / 100, m = rem % 100;
  const float* w = sel ? v_w : k_w;
  float acc = 0.f;
  for (int n = 0; n < 100; ++n) acc += proj_w[n * 131 + c] * w[m * 100 + n];
  ws[(sel ? WS_AV : WS_AK) + c * 100 + m] = acc;
}

// AkT frags: B[k][n] = Ak[n][k] (n<3), bf16
__global__ void pre_akt_kernel(const float* __restrict__ ws,
                               unsigned short* __restrict__ uw) {
  int idx = blockIdx.x * blockDim.x + threadIdx.x;
  if (idx >= 2048) return;
  int kt = idx >> 9, lane = (idx >> 3) & 63, j = idx & 7;
  int k = kt * 32 + (lane >> 4) * 8 + j;
  int n = lane & 15;
  float val = (k < 100 && n < 3) ? ws[WS_AK + n * 100 + k] : 0.f;
  uw[UW_AKT + idx] = f2bf(val);
}

// Zero/one pads: DkT k=100..127 -> 0 ; DvT n=100..111 -> (n==100 ? 1 : 0)
__global__ void pre_fill_kernel(unsigned short* __restrict__ uw) {
  int idx = blockIdx.x * blockDim.x + threadIdx.x;
  if (idx >= 40960) return;
  if (idx < 28672) {
    int m = 100 + idx % 28, p = idx / 28;
    int kt = m >> 5, ng = p >> 4;
    int lane = (((m & 31) >> 3) << 4) + (p & 15);
    uw[UW_DKT + ((kt * 64 + ng) * 64 + lane) * 8 + (m & 7)] = 0;
  } else {
    int r = idx - 28672;
    int m = 100 + r % 12, p = r / 12;
    int kv = p >> 5, nt = m >> 4;
    int lane = (((p & 31) >> 3) << 4) + (m & 15);
    uw[UW_DVT + ((kv * 7 + nt) * 64 + lane) * 8 + (p & 7)] =
        (m == 100) ? (unsigned short)0x3F80 : (unsigned short)0;
  }
}

// ---------------------------------------------------------------------------
// Dk/Dv (batch-independent K/V parts) straight into B-frag layouts (bf16)
// ---------------------------------------------------------------------------
__global__ void pre_dmat_kernel(const float* __restrict__ fm,
                                const float* __restrict__ proj_w,
                                const float* __restrict__ proj_b,
                                const float* __restrict__ k_w,
                                const float* __restrict__ k_b,
                                const float* __restrict__ v_w,
                                const float* __restrict__ v_b,
                                unsigned short* __restrict__ uw) {
  __shared__ float pos[8][128];
  __shared__ float tc[8][100];
  int p0 = blockIdx.x * 8;
  int tid = threadIdx.x;
  for (int idx = tid; idx < 1024; idx += 256) {
    int pl = idx >> 7, f = idx & 127;
    int p = p0 + pl;
    float cx = (float)(p & 31) * (1.f / 31.f);
    float cy = (float)(p >> 5) * (1.f / 31.f);
    int fi = f & 63;
    float pr = cx * fm[fi] + cy * fm[64 + fi];
    float ang = 6.2831853071795864769f * pr;
    pos[pl][f] = (f < 64) ? cosf(ang) : sinf(ang);
  }
  __syncthreads();
  for (int idx = tid; idx < 800; idx += 256) {
    int pl = idx / 100, n = idx % 100;
    float acc = proj_b[n];
    const float* pw = proj_w + n * 131 + 3;
    for (int f = 0; f < 128; ++f) acc += pos[pl][f] * pw[f];
    tc[pl][n] = acc;
  }
  __syncthreads();
  for (int idx = tid; idx < 1600; idx += 256) {
    int sel = idx / 800;
    int rem = idx % 800;
    int pl = rem / 100, m = rem % 100;
    int p = p0 + pl;
    const float* w = sel ? v_w : k_w;
    float acc = sel ? v_b[m] : k_b[m];
    for (int n = 0; n < 100; ++n) acc += tc[pl][n] * w[m * 100 + n];
    if (sel) {   // DvT: k=key p, n=chan m
      int kv = p >> 5, nt = m >> 4;
      int lane = (((p & 31) >> 3) << 4) + (m & 15);
      uw[UW_DVT + ((kv * 7 + nt) * 64 + lane) * 8 + (p & 7)] = f2bf(acc);
    } else {     // DkT: k=chan m, n=key p
      int kt = m >> 5, ng = p >> 4;
      int lane = (((m & 31) >> 3) << 4) + (p & 15);
      uw[UW_DKT + ((kt * 64 + ng) * 64 + lane) * 8 + (m & 7)] = f2bf(acc);
    }
  }
}

// ---------------------------------------------------------------------------
__global__ void pre_wfrag_kernel(const float* __restrict__ q_w,
                                 const float* __restrict__ o_w,
                                 const float* __restrict__ mlp_w1,
                                 const float* __restrict__ mlp_w2,
                                 const float* __restrict__ attn_in_w,
                                 const float* __restrict__ attn_out_w,
                                 unsigned short* __restrict__ uw) {
  int idx = blockIdx.x * 256 + threadIdx.x;
  if (idx >= UW_WCNT) return;
  float val = 0.f;
  if (idx < 14336) {
    int rem = idx;
    int kt = rem / 3584; rem %= 3584;
    int nt = rem / 512;  rem %= 512;
    int lane = rem >> 3, j = rem & 7;
    int k = kt * 32 + (lane >> 4) * 8 + j;
    int n = nt * 16 + (lane & 15);
    if (k < 100 && n < 100) val = q_w[n * 100 + k];
  } else if (idx < 28672) {
    int rem = idx - 14336;
    int kt = rem / 3584; rem %= 3584;
    int nt = rem / 512;  rem %= 512;
    int lane = rem >> 3, j = rem & 7;
    int k = kt * 32 + (lane >> 4) * 8 + j;
    int n = nt * 16 + (lane & 15);
    if (k < 100 && n < 100) val = o_w[n * 100 + k];
  } else if (idx < 131072) {
    int off = idx - 28672;
    int dd = off / 51200;
    int rem = off % 51200;
    int kt = rem / 12800; rem %= 12800;
    int nt = rem / 512;   rem %= 512;
    int lane = rem >> 3, j = rem & 7;
    int k = kt * 32 + (lane >> 4) * 8 + j;
    int n = nt * 16 + (lane & 15);
    if (k < 100) val = mlp_w1[dd * 40000 + n * 100 + k];
  } else if (idx < 231424) {
    int off = idx - 131072;
    int dd = off / 50176;
    int rem = off % 50176;
    int kt = rem / 3584; rem %= 3584;
    int nt = rem / 512;  rem %= 512;
    int lane = rem >> 3, j = rem & 7;
    int k = kt * 32 + (lane >> 4) * 8 + j;
    int n = nt * 16 + (lane & 15);
    if (k < 400 && n < 100) val = mlp_w2[dd * 40000 + n * 400 + k];
  } else if (idx < 329728) {
    int off = idx - 231424;
    int dw = off / 16384;
    int rem = off % 16384;
    int dd = dw / 3, wsel = dw % 3;
    int kt = rem / 4096; rem %= 4096;
    int nt = rem / 512;  rem %= 512;
    int lane = rem >> 3, j = rem & 7;
    int k = kt * 32 + (lane >> 4) * 8 + j;
    int np = nt * 16 + (lane & 15);
    int hh = np >> 5, dh = np & 31;
    if (k < 100 && dh < 25)
      val = attn_in_w[dd * 30000 + (wsel * 100 + hh * 25 + dh) * 100 + k];
  } else {
    int off = idx - 329728;
    int dd = off / 14336;
    int rem = off % 14336;
    int kt = rem / 3584; rem %= 3584;
    int nt = rem / 512;  rem %= 512;
    int lane = rem >> 3, j = rem & 7;
    int kp = kt * 32 + (lane >> 4) * 8 + j;
    int hh = kp >> 5, dh = kp & 31;
    int n = nt * 16 + (lane & 15);
    if (dh < 25 && n < 100)
      val = attn_out_w[dd * 10000 + n * 100 + hh * 25 + dh];
  }
  uw[UW_QW + idx] = f2bf(val);
}

// ---------------------------------------------------------------------------
// Main kernel: 1 block/batch, 512 threads (8 waves), 2 blocks/CU (80 KB LDS,
// 64 arch + 64 acc VGPR via __launch_bounds__(512,4) -> 16 waves/CU).
// Residual lat in MFMA C-layout f32 regs latC[mt2][nt][rg].
// Cross-attn: two per-m-tile passes; each pass loads only its own q-frags
// (16 regs, JIT) and computes qa in-pass. P scratch [16][76] lives in the
// PASS'S OWN 16-row s_M slice (dead after the aqp register load; rewritten
// by normalize only after P is dead). Tile loop: 0 barriers, ~95 live VGPRs.
// ---------------------------------------------------------------------------
__launch_bounds__(512, 4)
__global__ void perceiver_kernel(
    const float* __restrict__ x,
    const float* __restrict__ latents,
    const float* __restrict__ latent_pos,
    const float* __restrict__ q_b, const float* __restrict__ o_b,
    const float* __restrict__ ln1_g, const float* __restrict__ ln1_b,
    const float* __restrict__ attn_in_b, const float* __restrict__ attn_out_b,
    const float* __restrict__ ln2_g, const float* __restrict__ ln2_b,
    const float* __restrict__ mlp_b1, const float* __restrict__ mlp_b2,
    const float* __restrict__ ws,
    float* __restrict__ out) {
  __shared__ __align__(16) float s_pool[19908];
  float* s_sm = s_pool;                        // 2500 floats
  float* Rf   = s_pool + 2500;                 // 17408 floats = 34816 ushorts
  unsigned short* R   = (unsigned short*)Rf;
  unsigned short* s_M = R;                     // [256][132] bf16 staging
  // MHA aliases
  unsigned short* sQh   = R;                   // [256][36]
  unsigned short* kfrag = R + 9216;            // 8192
  unsigned short* vfrag = R + 17408;           // 8192
  unsigned short* sPm   = R + 25600;           // [256][36]

  const int tid  = threadIdx.x;
  const int b    = blockIdx.x;
  const int lane = tid & 63;
  const int wv   = tid >> 6;
  const int li   = lane & 15;
  const int lg   = lane >> 4;
  const unsigned short* uw = (const unsigned short*)(ws + WS_U);

  // ---- stage hot constants ----
  for (int i = tid; i < 200; i += 512) {
    s_sm[i] = ln1_g[i]; s_sm[200 + i] = ln1_b[i];
    s_sm[400 + i] = ln2_g[i]; s_sm[600 + i] = ln2_b[i];
  }
  for (int i = tid; i < 600; i += 512) s_sm[800 + i] = attn_in_b[i];
  for (int i = tid; i < 800; i += 512) s_sm[1400 + i] = mlp_b1[i];
  for (int i = tid; i < 300; i += 512) s_sm[2200 + i] = ws[WS_AV + i];
  __syncthreads();

  // ---- residual in C-layout regs ----
  f32x4 latC[2][7];
  #pragma unroll
  for (int mt2 = 0; mt2 < 2; ++mt2)
    #pragma unroll
    for (int nt = 0; nt < 7; ++nt) {
      const int col = nt * 16 + li;
      #pragma unroll
      for (int rg = 0; rg < 4; ++rg) {
        const int row = (2 * wv + mt2) * 16 + lg * 4 + rg;
        latC[mt2][nt][rg] = (col < 100)
            ? latents[row * 100 + col] + latent_pos[row * 100 + col] : 0.f;
      }
    }

  const float* xb = x + (long)b * 3072;

  // LN helper: latC -> s_M (bf16, zero-padded cols 100..127)
  auto ln_stage = [&](const float* gg, const float* bb) {
    #pragma unroll
    for (int mt2 = 0; mt2 < 2; ++mt2)
      #pragma unroll
      for (int rg = 0; rg < 4; ++rg) {
        float s = 0.f, sq = 0.f;
        #pragma unroll
        for (int nt = 0; nt < 7; ++nt) {
          const int col = nt * 16 + li;
          if (col < 100) { const float v = latC[mt2][nt][rg]; s += v; sq += v * v; }
        }
        s += __shfl_xor(s, 1); sq += __shfl_xor(sq, 1);
        s += __shfl_xor(s, 2); sq += __shfl_xor(sq, 2);
        s += __shfl_xor(s, 4); sq += __shfl_xor(sq, 4);
        s += __shfl_xor(s, 8); sq += __shfl_xor(sq, 8);
        const float mu = s * 0.01f;
        const float rs = rsqrtf(sq * 0.01f - mu * mu + 1e-5f);
        const int row = (2 * wv + mt2) * 16 + lg * 4 + rg;
        #pragma unroll
        for (int nt = 0; nt < 7; ++nt) {
          const int col = nt * 16 + li;
          s_M[row * 132 + col] = (col < 100)
              ? f2bf((latC[mt2][nt][rg] - mu) * rs * gg[col] + bb[col]) : 0;
        }
        s_M[row * 132 + 112 + li] = 0;
      }
  };

  // One per-m-tile cross-attn pass: loads own q-frags (JIT), computes qa,
  // runs tile loop (P scratch = own 16-row slice) + fixups + o-proj.
  auto cross_pass = [&](f32x4* latCp, int rowbase) {
    short8 aqp[4];
    #pragma unroll
    for (int kt = 0; kt < 4; ++kt)
      aqp[kt] = *(const short8*)(s_M + (rowbase + li) * 132 + kt * 32 + lg * 8);
    // P scratch [16][76] inside this pass's own (now-dead) row slice
    unsigned short* spw = R + rowbase * 132;

    // qa = q_s . Ak^T (C-layout; cols 0..2 valid)
    f32x4 qav = zero4();
    #pragma unroll
    for (int kt = 0; kt < 4; ++kt) {
      short8 bw = *(const short8*)(uw + UW_AKT + (kt * 64 + lane) * 8);
      qav = MFMA(aqp[kt], bw, qav);
    }
    float qa3[4][3];
    #pragma unroll
    for (int rg = 0; rg < 4; ++rg)
      #pragma unroll
      for (int ch = 0; ch < 3; ++ch)
        qa3[rg][ch] = __shfl(qav[rg], (lane & 48) + ch);

    f32x4 O7[7];
    #pragma unroll
    for (int nt = 0; nt < 7; ++nt) O7[nt] = zero4();
    float pxa[4][3];
    #pragma unroll
    for (int rg = 0; rg < 4; ++rg)
      #pragma unroll
      for (int ch = 0; ch < 3; ++ch) pxa[rg][ch] = 0.f;

    for (int t0 = 0; t0 < 1024; t0 += 64) {
      // S + exp + pxa + P-stage per ntk
      #pragma unroll
      for (int ntk = 0; ntk < 4; ++ntk) {
        f32x4 s0 = zero4();
        #pragma unroll
        for (int kt = 0; kt < 4; ++kt) {
          short8 bk = *(const short8*)(uw + UW_DKT + ((kt * 64 + (t0 >> 4) + ntk) * 64 + lane) * 8);
          s0 = MFMA(aqp[kt], bk, s0);
        }
        const int p = t0 + ntk * 16 + li;
        const float xr = xb[p], xg = xb[1024 + p], xv = xb[2048 + p];
        #pragma unroll
        for (int rg = 0; rg < 4; ++rg) {
          float sv = s0[rg] + qa3[rg][0] * xr + qa3[rg][1] * xg + qa3[rg][2] * xv;
          float pe = __expf(sv);
          pxa[rg][0] += pe * xr; pxa[rg][1] += pe * xg; pxa[rg][2] += pe * xv;
          spw[(lg * 4 + rg) * 76 + ntk * 16 + li] = f2bf(pe);
        }
      }
      // PV vs global DvT frags
      short8 ap0 = *(const short8*)(spw + li * 76 + lg * 8);
      short8 ap1 = *(const short8*)(spw + li * 76 + 32 + lg * 8);
      const int kv = t0 >> 5;
      #pragma unroll
      for (int nt = 0; nt < 7; ++nt) {
        short8 bv0 = *(const short8*)(uw + UW_DVT + ((kv * 7 + nt) * 64 + lane) * 8);
        short8 bv1 = *(const short8*)(uw + UW_DVT + (((kv + 1) * 7 + nt) * 64 + lane) * 8);
        O7[nt] = MFMA(ap0, bv0, O7[nt]);
        O7[nt] = MFMA(ap1, bv1, O7[nt]);
      }
    }

    // reduce pxa over 16-lane key groups
    #pragma unroll
    for (int rg = 0; rg < 4; ++rg)
      #pragma unroll
      for (int ch = 0; ch < 3; ++ch) {
        float v = pxa[rg][ch];
        v += __shfl_xor(v, 1);
        v += __shfl_xor(v, 2);
        v += __shfl_xor(v, 4);
        v += __shfl_xor(v, 8);
        pxa[rg][ch] = v;
      }
    // O += pxa . Av (cols < 100; col 100 (=l) untouched)
    #pragma unroll
    for (int nt = 0; nt < 7; ++nt) {
      const int col = nt * 16 + li;
      if (col < 100) {
        const float av0 = s_sm[2200 + col], av1 = s_sm[2300 + col], av2 = s_sm[2400 + col];
        #pragma unroll
        for (int rg = 0; rg < 4; ++rg)
          O7[nt][rg] += pxa[rg][0] * av0 + pxa[rg][1] * av1 + pxa[rg][2] * av2;
      }
    }
    // normalize (l at col 100 -> nt=6, li==4), write o_in -> s_M rows
    // (P scratch in these rows is dead now)
    #pragma unroll
    for (int rg = 0; rg < 4; ++rg) {
      const float lv = __shfl(O7[6][rg], (lane & 48) + 4);
      const float linv = 1.0f / lv;
      const int row = rowbase + lg * 4 + rg;
      #pragma unroll
      for (int nt = 0; nt < 7; ++nt) {
        const int col = nt * 16 + li;
        s_M[row * 132 + col] = (col < 100) ? f2bf(O7[nt][rg] * linv) : 0;
      }
      s_M[row * 132 + 112 + li] = 0;
    }
    // o-proj for this tile -> latCp
    short8 ao[4];
    #pragma unroll
    for (int kt = 0; kt < 4; ++kt)
      ao[kt] = *(const short8*)(s_M + (rowbase + li) * 132 + kt * 32 + lg * 8);
    #pragma unroll
    for (int nt = 0; nt < 7; ++nt) {
      f32x4 a0 = zero4();
      #pragma unroll
      for (int kt = 0; kt < 4; ++kt) {
        short8 bw = *(const short8*)(uw + UW_OW + ((kt * 7 + nt) * 64 + lane) * 8);
        a0 = MFMA(ao[kt], bw, a0);
      }
      const int col = nt * 16 + li;
      const float ob = (col < 100) ? o_b[col] : 0.f;
      #pragma unroll
      for (int rg = 0; rg < 4; ++rg)
        latCp[nt][rg] = (col < 100) ? a0[rg] + ob : 0.f;
    }
  };

  for (int it = 0; it < 8; ++it) {
    //=================== cross attention (barrier-free) ===================
    // stage lat -> s_M (own rows)
    #pragma unroll
    for (int mt2 = 0; mt2 < 2; ++mt2)
      #pragma unroll
      for (int rg = 0; rg < 4; ++rg) {
        const int row = (2 * wv + mt2) * 16 + lg * 4 + rg;
        #pragma unroll
        for (int nt = 0; nt < 7; ++nt) {
          const int col = nt * 16 + li;
          s_M[row * 132 + col] = (col < 100) ? f2bf(latC[mt2][nt][rg]) : 0;
        }
        s_M[row * 132 + 112 + li] = 0;
      }

    // q-proj: q_s = (lat @ q_w^T + q_b) * 0.1 -> s_M (own rows)
    {
      short8 aq[2][4];
      #pragma unroll
      for (int mt2 = 0; mt2 < 2; ++mt2)
        #pragma unroll
        for (int kt = 0; kt < 4; ++kt)
          aq[mt2][kt] = *(const short8*)(s_M + ((2 * wv + mt2) * 16 + li) * 132 + kt * 32 + lg * 8);
      #pragma unroll
      for (int nt = 0; nt < 7; ++nt) {
        f32x4 a0 = zero4(), a1 = zero4();
        #pragma unroll
        for (int kt = 0; kt < 4; ++kt) {
          short8 bw = *(const short8*)(uw + UW_QW + ((kt * 7 + nt) * 64 + lane) * 8);
          a0 = MFMA(aq[0][kt], bw, a0);
          a1 = MFMA(aq[1][kt], bw, a1);
        }
        const int col = nt * 16 + li;
        const float qb = (col < 100) ? q_b[col] : 0.f;
        #pragma unroll
        for (int rg = 0; rg < 4; ++rg) {
          const int r0 = (2 * wv) * 16 + lg * 4 + rg;
          const int r1 = (2 * wv + 1) * 16 + lg * 4 + rg;
          s_M[r0 * 132 + col] = (col < 100) ? f2bf((a0[rg] + qb) * 0.1f) : 0;
          s_M[r1 * 132 + col] = (col < 100) ? f2bf((a1[rg] + qb) * 0.1f) : 0;
        }
      }
    }

    cross_pass(latC[0], (2 * wv) * 16);
    cross_pass(latC[1], (2 * wv + 1) * 16);

    //=================== latent transformer ===================
    for (int d = 0; d < 2; ++d) {
      // ---- LN1 -> s_M (own rows)
      ln_stage(&s_sm[d * 100], &s_sm[200 + d * 100]);
      short8 ah[2][4];
      #pragma unroll
      for (int mt2 = 0; mt2 < 2; ++mt2)
        #pragma unroll
        for (int kt = 0; kt < 4; ++kt)
          ah[mt2][kt] = *(const short8*)(s_M + ((2 * wv + mt2) * 16 + li) * 132 + kt * 32 + lg * 8);

      // co init = lat + attn_out_b
      f32x4 co[2][7];
      #pragma unroll
      for (int nt = 0; nt < 7; ++nt) {
        const int col = nt * 16 + li;
        const float ob = (col < 100) ? attn_out_b[d * 100 + col] : 0.f;
        #pragma unroll
        for (int rg = 0; rg < 4; ++rg) {
          co[0][nt][rg] = (col < 100) ? latC[0][nt][rg] + ob : 0.f;
          co[1][nt][rg] = (col < 100) ? latC[1][nt][rg] + ob : 0.f;
        }
      }

      for (int h = 0; h < 4; ++h) {
        __syncthreads();   // prior reads of R complete before scratch writes
        #pragma unroll
        for (int ntd = 0; ntd < 2; ++ntd) {
          f32x4 cq0 = zero4(), cq1 = zero4(), ck0 = zero4(), ck1 = zero4(),
                cv0 = zero4(), cv1 = zero4();
          #pragma unroll
          for (int kt = 0; kt < 4; ++kt) {
            const int bidx = ((kt * 8 + h * 2 + ntd) * 64 + lane) * 8;
            short8 bq  = *(const short8*)(uw + UW_AIW + (d * 3 + 0) * 16384 + bidx);
            short8 bkk = *(const short8*)(uw + UW_AIW + (d * 3 + 1) * 16384 + bidx);
            short8 bvv = *(const short8*)(uw + UW_AIW + (d * 3 + 2) * 16384 + bidx);
            cq0 = MFMA(ah[0][kt], bq,  cq0); cq1 = MFMA(ah[1][kt], bq,  cq1);
            ck0 = MFMA(ah[0][kt], bkk, ck0); ck1 = MFMA(ah[1][kt], bkk, ck1);
            cv0 = MFMA(ah[0][kt], bvv, cv0); cv1 = MFMA(ah[1][kt], bvv, cv1);
          }
          const int dh = ntd * 16 + li;
          const bool ok = dh < 25;
          const float qb2 = ok ? s_sm[800 + d * 300 +       h * 25 + dh] : 0.f;
          const float kb2 = ok ? s_sm[800 + d * 300 + 100 + h * 25 + dh] : 0.f;
          const float vb2 = ok ? s_sm[800 + d * 300 + 200 + h * 25 + dh] : 0.f;
          #pragma unroll
          for (int mt2 = 0; mt2 < 2; ++mt2)
            #pragma unroll
            for (int rg = 0; rg < 4; ++rg) {
              const int rr = lg * 4 + rg;
              const int row = (2 * wv + mt2) * 16 + rr;
              const float q = mt2 ? cq1[rg] : cq0[rg];
              const float k = mt2 ? ck1[rg] : ck0[rg];
              const float v = mt2 ? cv1[rg] : cv0[rg];
              sQh[row * 36 + dh] = ok ? f2bf((q + qb2) * 0.2f) : 0;
              kfrag[((2 * wv + mt2) * 64 + (dh >> 3) * 16 + rr) * 8 + (dh & 7)] =
                  ok ? f2bf(k + kb2) : 0;
              vfrag[((wv * 2 + ntd) * 64 + (mt2 * 2 + (rr >> 3)) * 16 + li) * 8 + (rr & 7)] =
                  ok ? f2bf(v + vb2) : (unsigned short)((dh == 25) ? 0x3F80 : 0);
            }
        }
        __syncthreads();   // kfrag/vfrag visible

        short8 aqh0 = *(const short8*)(sQh + ((2 * wv + 0) * 16 + li) * 36 + lg * 8);
        short8 aqh1 = *(const short8*)(sQh + ((2 * wv + 1) * 16 + li) * 36 + lg * 8);
        f32x4 Oh00 = zero4(), Oh01 = zero4(), Oh10 = zero4(), Oh11 = zero4();
        for (int t = 0; t < 8; ++t) {
          short8 bk0 = *(const short8*)(kfrag + ((t * 2 + 0) * 64 + lane) * 8);
          short8 bk1 = *(const short8*)(kfrag + ((t * 2 + 1) * 64 + lane) * 8);
          f32x4 s00 = MFMA(aqh0, bk0, zero4());
          f32x4 s01 = MFMA(aqh0, bk1, zero4());
          f32x4 s10 = MFMA(aqh1, bk0, zero4());
          f32x4 s11 = MFMA(aqh1, bk1, zero4());
          #pragma unroll
          for (int rg = 0; rg < 4; ++rg) {
            const int r0 = (2 * wv) * 16 + lg * 4 + rg;
            const int r1 = (2 * wv + 1) * 16 + lg * 4 + rg;
            sPm[r0 * 36 + li]      = f2bf(__expf(s00[rg]));
            sPm[r0 * 36 + 16 + li] = f2bf(__expf(s01[rg]));
            sPm[r1 * 36 + li]      = f2bf(__expf(s10[rg]));
            sPm[r1 * 36 + 16 + li] = f2bf(__expf(s11[rg]));
          }
          short8 ap0 = *(const short8*)(sPm + ((2 * wv + 0) * 16 + li) * 36 + lg * 8);
          short8 ap1 = *(const short8*)(sPm + ((2 * wv + 1) * 16 + li) * 36 + lg * 8);
          short8 bv0 = *(const short8*)(vfrag + ((t * 2 + 0) * 64 + lane) * 8);
          short8 bv1 = *(const short8*)(vfrag + ((t * 2 + 1) * 64 + lane) * 8);
          Oh00 = MFMA(ap0, bv0, Oh00); Oh01 = MFMA(ap0, bv1, Oh01);
          Oh10 = MFMA(ap1, bv0, Oh10); Oh11 = MFMA(ap1, bv1, Oh11);
        }
        #pragma unroll
        for (int mt2 = 0; mt2 < 2; ++mt2)
          #pragma unroll
          for (int rg = 0; rg < 4; ++rg) {
            const f32x4& o0 = mt2 ? Oh10 : Oh00;
            const f32x4& o1 = mt2 ? Oh11 : Oh01;
            const float lv = __shfl(o1[rg], (lane & 48) + 9);
            const float linv = 1.0f / lv;
            const int row = (2 * wv + mt2) * 16 + lg * 4 + rg;
            sPm[row * 36 + li]      = (li < 25)      ? f2bf(o0[rg] * linv) : 0;
            sPm[row * 36 + 16 + li] = (16 + li < 25) ? f2bf(o1[rg] * linv) : 0;
          }
        short8 ao0 = *(const short8*)(sPm + ((2 * wv + 0) * 16 + li) * 36 + lg * 8);
        short8 ao1 = *(const short8*)(sPm + ((2 * wv + 1) * 16 + li) * 36 + lg * 8);
        #pragma unroll
        for (int nt = 0; nt < 7; ++nt) {
          short8 bw = *(const short8*)(uw + UW_AOW + d * 14336 + ((h * 7 + nt) * 64 + lane) * 8);
          co[0][nt] = MFMA(ao0, bw, co[0][nt]);
          co[1][nt] = MFMA(ao1, bw, co[1][nt]);
        }
      }
      __syncthreads();   // all scratch reads done

      #pragma unroll
      for (int mt2 = 0; mt2 < 2; ++mt2)
        #pragma unroll
        for (int nt = 0; nt < 7; ++nt) latC[mt2][nt] = co[mt2][nt];

      // ---- LN2 -> s_M, MLP
      ln_stage(&s_sm[400 + d * 100], &s_sm[600 + d * 100]);
      short8 ahm[2][4];
      #pragma unroll
      for (int mt2 = 0; mt2 < 2; ++mt2)
        #pragma unroll
        for (int kt = 0; kt < 4; ++kt)
          ahm[mt2][kt] = *(const short8*)(s_M + ((2 * wv + mt2) * 16 + li) * 132 + kt * 32 + lg * 8);

      f32x4 c2[2][7];
      #pragma unroll
      for (int nt = 0; nt < 7; ++nt) {
        const int col = nt * 16 + li;
        const float b2 = (col < 100) ? mlp_b2[d * 100 + col] : 0.f;
        #pragma unroll
        for (int rg = 0; rg < 4; ++rg) {
          c2[0][nt][rg] = (col < 100) ? latC[0][nt][rg] + b2 : 0.f;
          c2[1][nt][rg] = (col < 100) ? latC[1][nt][rg] + b2 : 0.f;
        }
      }

      const int w1off = UW_W1 + d * 51200;
      const int w2off = UW_W2 + d * 50176;
      for (int chunk = 0; chunk < 3; ++chunk) {
        #pragma unroll
        for (int ntl = 0; ntl < 8; ++ntl) {
          f32x4 a0 = zero4(), a1 = zero4();
          #pragma unroll
          for (int kt = 0; kt < 4; ++kt) {
            short8 bw = *(const short8*)(uw + w1off + ((kt * 25 + (chunk * 8 + ntl)) * 64 + lane) * 8);
            a0 = MFMA(ahm[0][kt], bw, a0);
            a1 = MFMA(ahm[1][kt], bw, a1);
          }
          const int col = ntl * 16 + li;
          const float bias = s_sm[1400 + d * 400 + chunk * 128 + col];
          #pragma unroll
          for (int rg = 0; rg < 4; ++rg) {
            const int r0 = (2 * wv) * 16 + lg * 4 + rg;
            const int r1 = (2 * wv + 1) * 16 + lg * 4 + rg;
            float h0 = a0[rg] + bias, h1 = a1[rg] + bias;
            s_M[r0 * 132 + col] = f2bf(0.5f * h0 * (1.0f + erff(h0 * 0.70710678118654752f)));
            s_M[r1 * 132 + col] = f2bf(0.5f * h1 * (1.0f + erff(h1 * 0.70710678118654752f)));
          }
        }
        #pragma unroll
        for (int ktl = 0; ktl < 4; ++ktl) {
          short8 ahh0 = *(const short8*)(s_M + ((2 * wv + 0) * 16 + li) * 132 + ktl * 32 + lg * 8);
          short8 ahh1 = *(const short8*)(s_M + ((2 * wv + 1) * 16 + li) * 132 + ktl * 32 + lg * 8);
          #pragma unroll
          for (int nt = 0; nt < 7; ++nt) {
            short8 bw = *(const short8*)(uw + w2off + (((chunk * 4 + ktl) * 7 + nt) * 64 + lane) * 8);
            c2[0][nt] = MFMA(ahh0, bw, c2[0][nt]);
            c2[1][nt] = MFMA(ahh1, bw, c2[1][nt]);
          }
        }
      }
      {   // chunk 3: hidden 384..399
        f32x4 a0 = zero4(), a1 = zero4();
        #pragma unroll
        for (int kt = 0; kt < 4; ++kt) {
          short8 bw = *(const short8*)(uw + w1off + ((kt * 25 + 24) * 64 + lane) * 8);
          a0 = MFMA(ahm[0][kt], bw, a0);
          a1 = MFMA(ahm[1][kt], bw, a1);
        }
        const float bias = s_sm[1400 + d * 400 + 384 + li];
        #pragma unroll
        for (int rg = 0; rg < 4; ++rg) {
          const int r0 = (2 * wv) * 16 + lg * 4 + rg;
          const int r1 = (2 * wv + 1) * 16 + lg * 4 + rg;
          float h0 = a0[rg] + bias, h1 = a1[rg] + bias;
          s_M[r0 * 132 + li] = f2bf(0.5f * h0 * (1.0f + erff(h0 * 0.70710678118654752f)));
          s_M[r1 * 132 + li] = f2bf(0.5f * h1 * (1.0f + erff(h1 * 0.70710678118654752f)));
          s_M[r0 * 132 + 16 + li] = 0;
          s_M[r1 * 132 + 16 + li] = 0;
        }
        short8 ahh0 = *(const short8*)(s_M + ((2 * wv + 0) * 16 + li) * 132 + lg * 8);
        short8 ahh1 = *(const short8*)(s_M + ((2 * wv + 1) * 16 + li) * 132 + lg * 8);
        #pragma unroll
        for (int nt = 0; nt < 7; ++nt) {
          short8 bw = *(const short8*)(uw + w2off + ((12 * 7 + nt) * 64 + lane) * 8);
          c2[0][nt] = MFMA(ahh0, bw, c2[0][nt]);
          c2[1][nt] = MFMA(ahh1, bw, c2[1][nt]);
        }
      }
      #pragma unroll
      for (int mt2 = 0; mt2 < 2; ++mt2)
        #pragma unroll
        for (int nt = 0; nt < 7; ++nt) latC[mt2][nt] = c2[mt2][nt];
    }
  }

  //=================== mean over 256 latents ===================
  __syncthreads();
  #pragma unroll
  for (int nt = 0; nt < 7; ++nt) {
    float v = 0.f;
    #pragma unroll
    for (int rg = 0; rg < 4; ++rg) v += latC[0][nt][rg] + latC[1][nt][rg];
    v += __shfl_xor(v, 16);
    v += __shfl_xor(v, 32);
    if (lg == 0) Rf[wv * 112 + nt * 16 + li] = v;
  }
  __syncthreads();
  if (tid < 100) {
    float s = 0.f;
    #pragma unroll
    for (int w = 0; w < 8; ++w) s += Rf[w * 112 + tid];
    out[b * 100 + tid] = s * (1.0f / 256.0f);
  }
}

// ---------------------------------------------------------------------------
extern "C" void kernel_launch(void* const* d_in, const int* in_sizes, int n_in,
                              void* d_out, int out_size, void* d_ws, size_t ws_size,
                              hipStream_t stream) {
  (void)in_sizes; (void)n_in; (void)out_size; (void)ws_size;
  const float* x          = (const float*)d_in[0];
  const float* latents    = (const float*)d_in[1];
  const float* latent_pos = (const float*)d_in[2];
  const float* fm         = (const float*)d_in[3];
  const float* proj_w     = (const float*)d_in[4];
  const float* proj_b     = (const float*)d_in[5];
  const float* q_w        = (const float*)d_in[6];
  const float* q_b        = (const float*)d_in[7];
  const float* k_w        = (const float*)d_in[8];
  const float* k_b        = (const float*)d_in[9];
  const float* v_w        = (const float*)d_in[10];
  const float* v_b        = (const float*)d_in[11];
  const float* o_w        = (const float*)d_in[12];
  const float* o_b        = (const float*)d_in[13];
  const float* ln1_g      = (const float*)d_in[14];
  const float* ln1_b      = (const float*)d_in[15];
  const float* attn_in_w  = (const float*)d_in[16];
  const float* attn_in_b  = (const float*)d_in[17];
  const float* attn_out_w = (const float*)d_in[18];
  const float* attn_out_b = (const float*)d_in[19];
  const float* ln2_g      = (const float*)d_in[20];
  const float* ln2_b      = (const float*)d_in[21];
  const float* mlp_w1     = (const float*)d_in[22];
  const float* mlp_b1     = (const float*)d_in[23];
  const float* mlp_w2     = (const float*)d_in[24];
  const float* mlp_b2     = (const float*)d_in[25];
  float* ws   = (float*)d_ws;
  float* outp = (float*)d_out;
  unsigned short* uw = (unsigned short*)(ws + WS_U);

  pre_amat_kernel<<<3, 256, 0, stream>>>(proj_w, k_w, v_w, ws);
  pre_akt_kernel<<<8, 256, 0, stream>>>(ws, uw);
  pre_dmat_kernel<<<128, 256, 0, stream>>>(fm, proj_w, proj_b, k_w, k_b, v_w, v_b, uw);
  pre_fill_kernel<<<160, 256, 0, stream>>>(uw);
  pre_wfrag_kernel<<<(UW_WCNT + 255) / 256, 256, 0, stream>>>(
      q_w, o_w, mlp_w1, mlp_w2, attn_in_w, attn_out_w, uw);
  perceiver_kernel<<<512, 512, 0, stream>>>(
      x, latents, latent_pos, q_b, o_b,
      ln1_g, ln1_b, attn_in_b, attn_out_b,
      ln2_g, ln2_b, mlp_b1, mlp_b2, ws, outp);
}